// Round 13
// baseline (859.575 us; speedup 1.0000x reference)
//
#include <hip/hip_runtime.h>

#define N_NODES 20000
#define N_EDGES 320000
#define R_RUNS 10
#define HID 64
#define NG 128
#define NC 10
#define NL 4
#define MROWS (R_RUNS * N_NODES)   // 200000
#define BN_EPS 1e-5f
#define NCOPY 16                   // stats copies per buffer
#define TS 72                      // LDS z-tile row stride (bf16 elems)
#define AG_NPB 8                   // ag1 nodes per block
#define G2_TILES 5                 // gemm64 64-row tiles per block
#define PB_NPB 16                  // pool_bn nodes per block

typedef __bf16 bf16;
typedef __attribute__((ext_vector_type(8))) __bf16 bf16x8;
typedef __attribute__((ext_vector_type(4))) float f32x4;
typedef unsigned int uint32;

// ---------------- workspace layout (bytes)
constexpr size_t OFF_FLAGS   = 0;          // int[4] counters, pad 256
constexpr size_t OFF_CURSOR  = 256;        // int[20001] -> pad 80384
constexpr size_t OFF_STATS   = 80640;      // f32[8 bufs][16 copies][128] = 65536
constexpr size_t OFF_POOLED5 = 146176;     // f32[5][128][64] = 163840
constexpr size_t ZERO_BYTES  = 310016;
constexpr size_t OFF_ROWST   = 310016;     // int[20001] -> pad 390400
constexpr size_t OFF_COL     = 390400;     // int[320000] -> 1670400
constexpr size_t OFF_PARAMS  = 1670400;    // bf16[37554] -> pad 1745664
constexpr size_t OFF_XB      = 1745664;    // bf16[1280000] -> 4305664
constexpr size_t OFF_H       = 4305664;    // 25,600,000
constexpr size_t OFF_Z       = 29905664;   // 25,600,000 -> end 55,505,664

// params block element offsets (w1/w2 stored PRE-SWIZZLED in B-fragment order)
#define PW1  0
#define PB1  16384
#define PG1  16640
#define PBB1 16896
#define PW2  17152
#define PB2  33536
#define PG2  33792
#define PBB2 34048
#define PFW  34304
#define PFB  37504
#define PTOT 37554
#define CVT_TOT (1280000 + PTOT)

// ---------------- runtime dtype detection (validated R4-R12) ----------------
__global__ void detect_kernel(const unsigned short* __restrict__ xu,
                              const unsigned int* __restrict__ mw,
                              int* __restrict__ cnts) {
    int tid = blockIdx.x * 256 + threadIdx.x;   // 16384 threads
    int insane = 0, lowp = 0, f32w = 0, gt1 = 0;
    for (int i = tid; i < 4096; i += 16384) {
        unsigned int u = xu[2 * i];
        if (((u >> 7) & 0xFFu) >= 0x90u) insane++;
    }
    for (int i = tid; i < 50000; i += 16384) {
        unsigned int w = mw[i];
        if ((w & 0xFFFFu) == 0x3F80u) lowp = 1;
        else if (w == 0x3F800000u) f32w = 1;
        else if (w > 1u) gt1 = 1;
    }
    if (insane) atomicAdd(&cnts[0], insane);
    if (lowp)   atomicOr(&cnts[1], 1);
    if (f32w)   atomicOr(&cnts[2], 1);
    if (gt1)    atomicOr(&cnts[3], 1);
}

__device__ inline bf16 ld_any(const void* p, int i, int f32mode) {
    if (f32mode) return (bf16)((const float*)p)[i];
    return ((const bf16*)p)[i];
}

__device__ inline int mask_dropped(const void* maskp, const int* cnts, size_t idx) {
    int w = cnts[1] ? 2 : (cnts[2] ? 4 : (cnts[3] ? 1 : 4));
    if (w == 1) return ((const unsigned char*)maskp)[idx] != 0;
    if (w == 2) return ((const unsigned short*)maskp)[idx] != 0;
    return ((const unsigned int*)maskp)[idx] != 0;
}

// convert all float inputs to canonical bf16; w1/w2 written in per-lane
// B-fragment order:
//   Wf[((nt*2+c)*64 + lane)*8 + j] = W[(c*32+(lane>>4)*8+j)*64 + nt*16+(lane&15)]
__global__ void convert_kernel(const int* __restrict__ cnts,
                               const void* x, const void* w1, const void* b1,
                               const void* g1, const void* bb1, const void* w2,
                               const void* b2, const void* g2, const void* bb2,
                               const void* fw, const void* fb,
                               bf16* __restrict__ xb, bf16* __restrict__ params) {
    int t = blockIdx.x * 256 + threadIdx.x;
    if (t >= CVT_TOT) return;
    int f = cnts[0] > 64;
    if (t < 1280000) { xb[t] = ld_any(x, t, f); return; }
    int u = t - 1280000;
    if (u < PB1 || (u >= PW2 && u < PB2)) {       // swizzled weight regions
        const void* src = (u < PB1) ? w1 : w2;
        int v = (u < PB1) ? u : u - PW2;
        int layer = v >> 12, rem = v & 4095;
        int j = rem & 7, lane = (rem >> 3) & 63, ntc = rem >> 9;
        int nt = ntc >> 1, c = ntc & 1;
        int k = c * 32 + (lane >> 4) * 8 + j;
        int n = nt * 16 + (lane & 15);
        params[u] = ld_any(src, layer * 4096 + k * 64 + n, f);
        return;
    }
    const void* src; int base;
    if      (u < PG1)  { src = b1;  base = PB1; }
    else if (u < PBB1) { src = g1;  base = PG1; }
    else if (u < PW2)  { src = bb1; base = PBB1; }
    else if (u < PG2)  { src = b2;  base = PB2; }
    else if (u < PBB2) { src = g2;  base = PG2; }
    else if (u < PFW)  { src = bb2; base = PBB2; }
    else if (u < PFB)  { src = fw;  base = PFW; }
    else               { src = fb;  base = PFB; }
    params[u] = ld_any(src, u - base, f);
}

// h0[(n*10+r)*64+f] = drop[r][n] ? 0 : x[n,f]  (contiguous writes, R7-proven)
__global__ void build_h0_kernel(const bf16* __restrict__ xb, const void* __restrict__ maskp,
                                const int* __restrict__ cnts, bf16* __restrict__ h) {
    int i = blockIdx.x * 256 + threadIdx.x;   // (n*10+r)*8 + c ; 1.6M total
    int c = i & 7;
    int rowid = i >> 3;
    int r = rowid % R_RUNS;
    int n = rowid / R_RUNS;
    int dropped = mask_dropped(maskp, cnts, (size_t)r * N_NODES + n);
    bf16x8 v;
    if (dropped) {
        #pragma unroll
        for (int j = 0; j < 8; ++j) v[j] = (bf16)0.0f;
    } else {
        v = *(const bf16x8*)(xb + (size_t)n * HID + c * 8);
    }
    *(bf16x8*)(h + (size_t)rowid * HID + c * 8) = v;
}

// level-0 pool, algebraic: pooled[g,f] += x[n,f] * (#non-dropped runs)/R.
// Reads xb (2.5MB) + mask counts instead of the 25.6MB h buffer.
__global__ void pool0_kernel(const bf16* __restrict__ xb, const void* __restrict__ maskp,
                             const int* __restrict__ cnts, const int* __restrict__ batch,
                             float* __restrict__ pooled) {
    int t = blockIdx.x * 256 + threadIdx.x;   // n*8 + c ; 160000
    int c = t & 7, n = t >> 3;
    int cnt = 0;
    #pragma unroll
    for (int r = 0; r < R_RUNS; ++r)
        cnt += !mask_dropped(maskp, cnts, (size_t)r * N_NODES + n);
    bf16x8 xv = *(const bf16x8*)(xb + (size_t)n * HID + c * 8);
    float sc = (float)cnt * (1.0f / R_RUNS);
    int g = batch[n];
    #pragma unroll
    for (int j = 0; j < 8; ++j)
        atomicAdd(&pooled[g * HID + c * 8 + j], (float)xv[j] * sc);
}

// ---------------- CSR build (keyed by dst) ----------------
__global__ void csr_count_kernel(const int* __restrict__ ei, int* __restrict__ deg) {
    int e = blockIdx.x * 256 + threadIdx.x;
    if (e < N_EDGES) atomicAdd(&deg[ei[N_EDGES + e]], 1);
}

__global__ void csr_scan_kernel(int* __restrict__ deg, int* __restrict__ row_start) {
    __shared__ int lds[1024];
    int tid = threadIdx.x;
    const int CH = 20;
    int base = tid * CH;
    int local[CH];
    int s = 0;
    #pragma unroll
    for (int j = 0; j < CH; ++j) {
        int n = base + j;
        int d = (n < N_NODES) ? deg[n] : 0;
        local[j] = d; s += d;
    }
    lds[tid] = s; __syncthreads();
    for (int off = 1; off < 1024; off <<= 1) {
        int add = (tid >= off) ? lds[tid - off] : 0;
        __syncthreads();
        lds[tid] += add;
        __syncthreads();
    }
    int excl = lds[tid] - s;
    #pragma unroll
    for (int j = 0; j < CH; ++j) {
        int n = base + j;
        if (n < N_NODES) { row_start[n] = excl; deg[n] = excl; excl += local[j]; }
    }
    if (tid == 1023) row_start[N_NODES] = lds[1023];
}

__global__ void csr_fill_kernel(const int* __restrict__ ei, int* __restrict__ cursor,
                                int* __restrict__ col) {
    int e = blockIdx.x * 256 + threadIdx.x;
    if (e < N_EDGES) {
        int src = ei[e];
        int dst = ei[N_EDGES + e];
        int pos = atomicAdd(&cursor[dst], 1);
        col[pos] = src;
    }
}

// per-neighbor accumulate helper
#define AG_ACC(a_, t_)                                                         \
    {                                                                          \
        uint32 wd[4] = {(a_).x, (a_).y, (a_).z, (a_).w};                       \
        _Pragma("unroll")                                                      \
        for (int c = 0; c < 4; ++c) {                                          \
            acc[2 * c]     += __uint_as_float(wd[c] << 16);                    \
            acc[2 * c + 1] += __uint_as_float(wd[c] & 0xFFFF0000u);            \
        }                                                                      \
        acc[8] += __uint_as_float((t_) << 16);                                 \
        acc[9] += __uint_as_float((t_) & 0xFFFF0000u);                         \
    }

// ---------------- fused agg + gemm1: block = 8 nodes (80 rows), grid 2500.
// R13: 8-deep neighbor unroll (18 loads in flight/wave — split-agg's MLP,
// which ran the same traffic at 3.6 TB/s vs ag1-R12's 2.45).
__global__ __launch_bounds__(256) void ag1_kernel(const uint32* __restrict__ hD,
                                                  const int* __restrict__ row_start,
                                                  const int* __restrict__ col,
                                                  const bf16* __restrict__ Wf,
                                                  const bf16* __restrict__ bias,
                                                  bf16* __restrict__ out,
                                                  float* __restrict__ statsOut) {
    __shared__ __align__(16) bf16 zT[AG_NPB * R_RUNS * TS];   // 80 x 72 = 11520 B
    __shared__ float lsum[64], lsq[64];
    uint32* zTu = (uint32*)zT;                                // row stride 36 dwords
    int tid = threadIdx.x;
    int wave = tid >> 6, lane = tid & 63, l16 = lane & 15, quad = lane >> 4;
    int b = blockIdx.x;
    const int NODE_DW = R_RUNS * HID / 2;   // 320

    if (tid < 64) { lsum[tid] = 0.f; lsq[tid] = 0.f; }

    // ---- phase 1: aggregate 2 nodes per wave into LDS
    for (int i = 0; i < AG_NPB / 4; ++i) {
        int nl = wave + 4 * i;              // local node 0..7
        int n = b * AG_NPB + nl;
        size_t base4 = (size_t)n * NODE_DW + lane * 4;
        size_t baset = (size_t)n * NODE_DW + 256 + lane;
        float acc[10];
        {
            uint4 u = *(const uint4*)(hD + base4);
            uint32 tw = hD[baset];
            acc[0] = __uint_as_float(u.x << 16); acc[1] = __uint_as_float(u.x & 0xFFFF0000u);
            acc[2] = __uint_as_float(u.y << 16); acc[3] = __uint_as_float(u.y & 0xFFFF0000u);
            acc[4] = __uint_as_float(u.z << 16); acc[5] = __uint_as_float(u.z & 0xFFFF0000u);
            acc[6] = __uint_as_float(u.w << 16); acc[7] = __uint_as_float(u.w & 0xFFFF0000u);
            acc[8] = __uint_as_float(tw << 16);  acc[9] = __uint_as_float(tw & 0xFFFF0000u);
        }
        int beg = row_start[n], end = row_start[n + 1];
        int idx = beg;
        for (; idx + 8 <= end; idx += 8) {
            uint4 a[8]; uint32 tw[8];
            #pragma unroll
            for (int u = 0; u < 8; ++u) {
                size_t o = (size_t)col[idx + u] * NODE_DW;
                a[u] = *(const uint4*)(hD + o + lane * 4);
                tw[u] = hD[o + 256 + lane];
            }
            #pragma unroll
            for (int u = 0; u < 8; ++u) AG_ACC(a[u], tw[u]);
        }
        for (; idx + 4 <= end; idx += 4) {
            uint4 a[4]; uint32 tw[4];
            #pragma unroll
            for (int u = 0; u < 4; ++u) {
                size_t o = (size_t)col[idx + u] * NODE_DW;
                a[u] = *(const uint4*)(hD + o + lane * 4);
                tw[u] = hD[o + 256 + lane];
            }
            #pragma unroll
            for (int u = 0; u < 4; ++u) AG_ACC(a[u], tw[u]);
        }
        for (; idx < end; ++idx) {
            size_t o = (size_t)col[idx] * NODE_DW;
            uint4 a0 = *(const uint4*)(hD + o + lane * 4);
            uint32 t0 = hD[o + 256 + lane];
            AG_ACC(a0, t0);
        }
        #pragma unroll
        for (int c = 0; c < 5; ++c) {
            int d = (c < 4) ? (lane * 4 + c) : (256 + lane);
            int rL = nl * R_RUNS + (d >> 5);
            int fp = d & 31;
            unsigned short lo = __builtin_bit_cast(unsigned short, (bf16)acc[2 * c]);
            unsigned short hi = __builtin_bit_cast(unsigned short, (bf16)acc[2 * c + 1]);
            zTu[rL * (TS / 2) + fp] = (uint32)lo | ((uint32)hi << 16);
        }
    }
    __syncthreads();

    // ---- phase 2: gemm1 from LDS, 5 row-groups of 16 over 4 waves
    bf16x8 bfr[4][2];
    #pragma unroll
    for (int nt = 0; nt < 4; ++nt)
        #pragma unroll
        for (int c = 0; c < 2; ++c)
            bfr[nt][c] = *(const bf16x8*)(Wf + (size_t)((nt * 2 + c) * 64 + lane) * 8);
    float bvs[4];
    #pragma unroll
    for (int nt = 0; nt < 4; ++nt) bvs[nt] = (float)bias[nt * 16 + l16];

    for (int g = wave; g < 5; g += 4) {
        const bf16* tp = &zT[(g * 16 + l16) * TS];
        bf16x8 a0 = *(const bf16x8*)(tp + quad * 8);
        bf16x8 a1 = *(const bf16x8*)(tp + 32 + quad * 8);
        f32x4 acc[4];
        #pragma unroll
        for (int nt = 0; nt < 4; ++nt) acc[nt] = (f32x4){bvs[nt], bvs[nt], bvs[nt], bvs[nt]};
        #pragma unroll
        for (int nt = 0; nt < 4; ++nt) {
            acc[nt] = __builtin_amdgcn_mfma_f32_16x16x32_bf16(a0, bfr[nt][0], acc[nt], 0, 0, 0);
            acc[nt] = __builtin_amdgcn_mfma_f32_16x16x32_bf16(a1, bfr[nt][1], acc[nt], 0, 0, 0);
        }
        size_t rowBase = (size_t)b * (AG_NPB * R_RUNS) + g * 16;
        #pragma unroll
        for (int nt = 0; nt < 4; ++nt) {
            float ss = 0.f, qq = 0.f;
            #pragma unroll
            for (int reg = 0; reg < 4; ++reg) {
                float v = acc[nt][reg];
                ss += v; qq += v * v;
                out[(rowBase + quad * 4 + reg) * HID + nt * 16 + l16] = (bf16)v;
            }
            atomicAdd(&lsum[nt * 16 + l16], ss);
            atomicAdd(&lsq[nt * 16 + l16], qq);
        }
    }
    __syncthreads();
    if (tid < 64) {
        int copy = b & (NCOPY - 1);
        atomicAdd(&statsOut[copy * 128 + tid], lsum[tid]);
        atomicAdd(&statsOut[copy * 128 + 64 + tid], lsq[tid]);
    }
}

// ---------------- gemm2: 320 rows/block (5 tiles of 64), grid 625 (R12-proven).
__global__ __launch_bounds__(256) void gemm64_kernel(const bf16* in,
                                                     const bf16* __restrict__ Wf,
                                                     const bf16* __restrict__ bias,
                                                     bf16* out,
                                                     const float* __restrict__ statsIn,
                                                     const bf16* __restrict__ gammaIn,
                                                     const bf16* __restrict__ betaIn,
                                                     float* __restrict__ statsOut) {
    __shared__ float lstat[128];
    __shared__ float lscale[64], lshift[64];
    __shared__ float lsum[64], lsq[64];
    int tid = threadIdx.x;
    int wave = tid >> 6, lane = tid & 63, l16 = lane & 15, quad = lane >> 4;

    if (tid < 128) {
        float s = 0.f;
        #pragma unroll
        for (int k = 0; k < NCOPY; ++k) s += statsIn[k * 128 + tid];
        lstat[tid] = s;
    }
    if (tid < 64) { lsum[tid] = 0.f; lsq[tid] = 0.f; }
    __syncthreads();
    if (tid < 64) {
        float mu = lstat[tid] * (1.0f / MROWS);
        float var = lstat[tid + 64] * (1.0f / MROWS) - mu * mu;
        float rs = rsqrtf(var + BN_EPS);
        float a = (float)gammaIn[tid] * rs;
        lscale[tid] = a;
        lshift[tid] = (float)betaIn[tid] - mu * a;
    }
    __syncthreads();

    bf16x8 bfrag[4][2];
    #pragma unroll
    for (int nt = 0; nt < 4; ++nt)
        #pragma unroll
        for (int c = 0; c < 2; ++c)
            bfrag[nt][c] = *(const bf16x8*)(Wf + (size_t)((nt * 2 + c) * 64 + lane) * 8);
    float bvs[4];
    #pragma unroll
    for (int nt = 0; nt < 4; ++nt) bvs[nt] = (float)bias[nt * 16 + l16];

    for (int t5 = 0; t5 < G2_TILES; ++t5) {
        size_t rowBase = (size_t)blockIdx.x * (G2_TILES * 64) + t5 * 64 + wave * 16;
        f32x4 acc[4];
        #pragma unroll
        for (int nt = 0; nt < 4; ++nt) acc[nt] = (f32x4){bvs[nt], bvs[nt], bvs[nt], bvs[nt]};

        size_t row = rowBase + l16;
        bf16x8 afrag[2];
        #pragma unroll
        for (int c = 0; c < 2; ++c) {
            int k0 = c * 32 + quad * 8;
            bf16x8 v = *(const bf16x8*)(in + row * HID + k0);
            #pragma unroll
            for (int j = 0; j < 8; ++j) {
                float f = (float)v[j] * lscale[k0 + j] + lshift[k0 + j];
                v[j] = (bf16)fmaxf(f, 0.f);
            }
            afrag[c] = v;
        }

        #pragma unroll
        for (int nt = 0; nt < 4; ++nt) {
            acc[nt] = __builtin_amdgcn_mfma_f32_16x16x32_bf16(afrag[0], bfrag[nt][0], acc[nt], 0, 0, 0);
            acc[nt] = __builtin_amdgcn_mfma_f32_16x16x32_bf16(afrag[1], bfrag[nt][1], acc[nt], 0, 0, 0);
        }

        #pragma unroll
        for (int nt = 0; nt < 4; ++nt) {
            float s = 0.f, q = 0.f;
            #pragma unroll
            for (int reg = 0; reg < 4; ++reg) {
                float v = acc[nt][reg];
                s += v; q += v * v;
                out[(rowBase + quad * 4 + reg) * HID + nt * 16 + l16] = (bf16)v;
            }
            atomicAdd(&lsum[nt * 16 + l16], s);
            atomicAdd(&lsq[nt * 16 + l16], q);
        }
    }
    __syncthreads();
    if (tid < 64) {
        int copy = blockIdx.x & (NCOPY - 1);
        atomicAdd(&statsOut[copy * 128 + tid], lsum[tid]);
        atomicAdd(&statsOut[copy * 128 + 64 + tid], lsq[tid]);
    }
}

// fused stats reduce + BN+ReLU + h-materialize + pool; 16 nodes/block (R12-proven).
__global__ __launch_bounds__(256) void pool_bn_kernel(const bf16* __restrict__ t,
                                                      const float* __restrict__ statsIn,
                                                      const bf16* __restrict__ gammaIn,
                                                      const bf16* __restrict__ betaIn,
                                                      bf16* __restrict__ hOut,
                                                      const int* __restrict__ batch,
                                                      float* __restrict__ pooled) {
    __shared__ float lstat[128], lscale[64], lshift[64];
    int tid = threadIdx.x;
    if (tid < 128) {
        float s = 0.f;
        #pragma unroll
        for (int k = 0; k < NCOPY; ++k) s += statsIn[k * 128 + tid];
        lstat[tid] = s;
    }
    __syncthreads();
    if (tid < 64) {
        float mu = lstat[tid] * (1.0f / MROWS);
        float var = lstat[tid + 64] * (1.0f / MROWS) - mu * mu;
        float rs = rsqrtf(var + BN_EPS);
        float a = (float)gammaIn[tid] * rs;
        lscale[tid] = a;
        lshift[tid] = (float)betaIn[tid] - mu * a;
    }
    __syncthreads();
    int f = tid & 63, nsub = tid >> 6;
    float sc = lscale[f], sh = lshift[f];
    #pragma unroll
    for (int j = 0; j < PB_NPB / 4; ++j) {
        int n = blockIdx.x * PB_NPB + j * 4 + nsub;
        size_t base = (size_t)n * (R_RUNS * HID) + f;
        float s = 0.f;
        #pragma unroll
        for (int r = 0; r < R_RUNS; ++r) {
            float v = (float)t[base + r * HID];
            v = fmaxf(v * sc + sh, 0.f);
            hOut[base + r * HID] = (bf16)v;
            s += v;
        }
        atomicAdd(&pooled[batch[n] * HID + f], s * (1.0f / R_RUNS));
    }
}

// final: out[g,:] = log_softmax( sum_l pooled5[l][g] @ fcw_l + fcb_l )
__global__ void fc_softmax_kernel(const float* __restrict__ pooled5,
                                  const bf16* __restrict__ params,
                                  const int* __restrict__ cnts, void* __restrict__ out) {
    int g = threadIdx.x;   // 128 threads
    if (g >= NG) return;
    float o[NC];
    #pragma unroll
    for (int c = 0; c < NC; ++c) o[c] = 0.f;
    for (int l = 0; l < NL + 1; ++l) {
        const float* pg = pooled5 + ((size_t)l * NG + g) * HID;
        const bf16* fw = params + PFW + l * (HID * NC);
        for (int k = 0; k < HID; ++k) {
            float p = pg[k];
            #pragma unroll
            for (int c = 0; c < NC; ++c) o[c] += p * (float)fw[k * NC + c];
        }
        #pragma unroll
        for (int c = 0; c < NC; ++c) o[c] += (float)params[PFB + l * NC + c];
    }
    float m = -1e30f;
    #pragma unroll
    for (int c = 0; c < NC; ++c) m = fmaxf(m, o[c]);
    float s = 0.f;
    #pragma unroll
    for (int c = 0; c < NC; ++c) s += expf(o[c] - m);
    float lg = logf(s);
    int f = cnts[0] > 64;
    #pragma unroll
    for (int c = 0; c < NC; ++c) {
        float val = o[c] - m - lg;
        if (f) ((float*)out)[g * NC + c] = val;
        else   ((bf16*)out)[g * NC + c] = (bf16)val;
    }
}

extern "C" void kernel_launch(void* const* d_in, const int* in_sizes, int n_in,
                              void* d_out, int out_size, void* d_ws, size_t ws_size,
                              hipStream_t stream) {
    const void* x     = d_in[0];
    const int*  ei    = (const int*)d_in[1];
    const int*  batch = (const int*)d_in[2];
    const void* maskp = d_in[3];

    char* ws = (char*)d_ws;
    int*   cnts    = (int*)(ws + OFF_FLAGS);
    int*   cursor  = (int*)(ws + OFF_CURSOR);
    float* statsb  = (float*)(ws + OFF_STATS);
    float* pooled5 = (float*)(ws + OFF_POOLED5);
    int*   rowst   = (int*)(ws + OFF_ROWST);
    int*   colbuf  = (int*)(ws + OFF_COL);
    bf16*  params  = (bf16*)(ws + OFF_PARAMS);
    bf16*  xb      = (bf16*)(ws + OFF_XB);
    bf16*  h       = (bf16*)(ws + OFF_H);
    bf16*  z       = (bf16*)(ws + OFF_Z);

    hipMemsetAsync(ws, 0, ZERO_BYTES, stream);   // flags+cursor+stats+pooled5

    detect_kernel<<<64, 256, 0, stream>>>((const unsigned short*)x,
                                          (const unsigned int*)maskp, cnts);
    convert_kernel<<<(CVT_TOT + 255) / 256, 256, 0, stream>>>(
        cnts, x, d_in[4], d_in[5], d_in[6], d_in[7], d_in[8], d_in[9], d_in[10],
        d_in[11], d_in[12], d_in[13], xb, params);

    csr_count_kernel<<<(N_EDGES + 255) / 256, 256, 0, stream>>>(ei, cursor);
    csr_scan_kernel<<<1, 1024, 0, stream>>>(cursor, rowst);
    csr_fill_kernel<<<(N_EDGES + 255) / 256, 256, 0, stream>>>(ei, cursor, colbuf);

    build_h0_kernel<<<(MROWS * 8) / 256, 256, 0, stream>>>(xb, maskp, cnts, h);
    pool0_kernel<<<(N_NODES * 8) / 256, 256, 0, stream>>>(xb, maskp, cnts, batch, pooled5);

    for (int i = 0; i < NL; ++i) {
        float* st1 = statsb + (size_t)(2 * i) * (NCOPY * 128);
        float* st2 = statsb + (size_t)(2 * i + 1) * (NCOPY * 128);

        ag1_kernel<<<N_NODES / AG_NPB, 256, 0, stream>>>(
            (const uint32*)h, rowst, colbuf,
            params + PW1 + i * 4096, params + PB1 + i * 64, z, st1);

        gemm64_kernel<<<MROWS / (G2_TILES * 64), 256, 0, stream>>>(
            z, params + PW2 + i * 4096, params + PB2 + i * 64, z,
            st1, params + PG1 + i * 64, params + PBB1 + i * 64, st2);

        pool_bn_kernel<<<N_NODES / PB_NPB, 256, 0, stream>>>(
            z, st2, params + PG2 + i * 64, params + PBB2 + i * 64, h, batch,
            pooled5 + (size_t)(i + 1) * NG * HID);
    }

    fc_softmax_kernel<<<1, 128, 0, stream>>>(pooled5, params, cnts, d_out);
}

// Round 14
// 772.844 us; speedup vs baseline: 1.1122x; 1.1122x over previous
//
#include <hip/hip_runtime.h>

#define N_NODES 20000
#define N_EDGES 320000
#define R_RUNS 10
#define HID 64
#define NG 128
#define NC 10
#define NL 4
#define MROWS (R_RUNS * N_NODES)   // 200000
#define BN_EPS 1e-5f
#define NCOPY 16                   // stats copies per buffer
#define TS 72                      // LDS z-tile row stride (bf16 elems)
#define AG_NPB 8                   // ag1 nodes per block (R12-proven)
#define G2_TILES 5                 // gemm64 64-row tiles per block
#define PB_NPB 16                  // pool_bn nodes per block
#define PB_SLOTS 4                 // pool_bn LDS graph slots
#define P0_NPB 32                  // pool0 nodes per block
#define P0_SLOTS 6                 // pool0 LDS graph slots

typedef __bf16 bf16;
typedef __attribute__((ext_vector_type(8))) __bf16 bf16x8;
typedef __attribute__((ext_vector_type(4))) float f32x4;
typedef unsigned int uint32;

// ---------------- workspace layout (bytes)
constexpr size_t OFF_FLAGS   = 0;          // int[4] counters, pad 256
constexpr size_t OFF_CURSOR  = 256;        // int[20001] -> pad 80384
constexpr size_t OFF_STATS   = 80640;      // f32[8 bufs][16 copies][128] = 65536
constexpr size_t OFF_POOLED5 = 146176;     // f32[5][128][64] = 163840
constexpr size_t ZERO_BYTES  = 310016;
constexpr size_t OFF_ROWST   = 310016;     // int[20001] -> pad 390400
constexpr size_t OFF_COL     = 390400;     // int[320000] -> 1670400
constexpr size_t OFF_PARAMS  = 1670400;    // bf16[37554] -> pad 1745664
constexpr size_t OFF_XB      = 1745664;    // bf16[1280000] -> 4305664
constexpr size_t OFF_H       = 4305664;    // 25,600,000
constexpr size_t OFF_Z       = 29905664;   // 25,600,000 -> end 55,505,664

// params block element offsets (w1/w2 stored PRE-SWIZZLED in B-fragment order)
#define PW1  0
#define PB1  16384
#define PG1  16640
#define PBB1 16896
#define PW2  17152
#define PB2  33536
#define PG2  33792
#define PBB2 34048
#define PFW  34304
#define PFB  37504
#define PTOT 37554
#define CVT_TOT (1280000 + PTOT)

// ---------------- runtime dtype detection (validated R4-R13) ----------------
__global__ void detect_kernel(const unsigned short* __restrict__ xu,
                              const unsigned int* __restrict__ mw,
                              int* __restrict__ cnts) {
    int tid = blockIdx.x * 256 + threadIdx.x;   // 16384 threads
    int insane = 0, lowp = 0, f32w = 0, gt1 = 0;
    for (int i = tid; i < 4096; i += 16384) {
        unsigned int u = xu[2 * i];
        if (((u >> 7) & 0xFFu) >= 0x90u) insane++;
    }
    for (int i = tid; i < 50000; i += 16384) {
        unsigned int w = mw[i];
        if ((w & 0xFFFFu) == 0x3F80u) lowp = 1;
        else if (w == 0x3F800000u) f32w = 1;
        else if (w > 1u) gt1 = 1;
    }
    if (insane) atomicAdd(&cnts[0], insane);
    if (lowp)   atomicOr(&cnts[1], 1);
    if (f32w)   atomicOr(&cnts[2], 1);
    if (gt1)    atomicOr(&cnts[3], 1);
}

__device__ inline bf16 ld_any(const void* p, int i, int f32mode) {
    if (f32mode) return (bf16)((const float*)p)[i];
    return ((const bf16*)p)[i];
}

__device__ inline int mask_dropped(const void* maskp, const int* cnts, size_t idx) {
    int w = cnts[1] ? 2 : (cnts[2] ? 4 : (cnts[3] ? 1 : 4));
    if (w == 1) return ((const unsigned char*)maskp)[idx] != 0;
    if (w == 2) return ((const unsigned short*)maskp)[idx] != 0;
    return ((const unsigned int*)maskp)[idx] != 0;
}

// convert all float inputs to canonical bf16; w1/w2 written in per-lane
// B-fragment order:
//   Wf[((nt*2+c)*64 + lane)*8 + j] = W[(c*32+(lane>>4)*8+j)*64 + nt*16+(lane&15)]
__global__ void convert_kernel(const int* __restrict__ cnts,
                               const void* x, const void* w1, const void* b1,
                               const void* g1, const void* bb1, const void* w2,
                               const void* b2, const void* g2, const void* bb2,
                               const void* fw, const void* fb,
                               bf16* __restrict__ xb, bf16* __restrict__ params) {
    int t = blockIdx.x * 256 + threadIdx.x;
    if (t >= CVT_TOT) return;
    int f = cnts[0] > 64;
    if (t < 1280000) { xb[t] = ld_any(x, t, f); return; }
    int u = t - 1280000;
    if (u < PB1 || (u >= PW2 && u < PB2)) {       // swizzled weight regions
        const void* src = (u < PB1) ? w1 : w2;
        int v = (u < PB1) ? u : u - PW2;
        int layer = v >> 12, rem = v & 4095;
        int j = rem & 7, lane = (rem >> 3) & 63, ntc = rem >> 9;
        int nt = ntc >> 1, c = ntc & 1;
        int k = c * 32 + (lane >> 4) * 8 + j;
        int n = nt * 16 + (lane & 15);
        params[u] = ld_any(src, layer * 4096 + k * 64 + n, f);
        return;
    }
    const void* src; int base;
    if      (u < PG1)  { src = b1;  base = PB1; }
    else if (u < PBB1) { src = g1;  base = PG1; }
    else if (u < PW2)  { src = bb1; base = PBB1; }
    else if (u < PG2)  { src = b2;  base = PB2; }
    else if (u < PBB2) { src = g2;  base = PG2; }
    else if (u < PFW)  { src = bb2; base = PBB2; }
    else if (u < PFB)  { src = fw;  base = PFW; }
    else               { src = fb;  base = PFB; }
    params[u] = ld_any(src, u - base, f);
}

// h0[(n*10+r)*64+f] = drop[r][n] ? 0 : x[n,f]  (contiguous writes, R7-proven)
__global__ void build_h0_kernel(const bf16* __restrict__ xb, const void* __restrict__ maskp,
                                const int* __restrict__ cnts, bf16* __restrict__ h) {
    int i = blockIdx.x * 256 + threadIdx.x;   // (n*10+r)*8 + c ; 1.6M total
    int c = i & 7;
    int rowid = i >> 3;
    int r = rowid % R_RUNS;
    int n = rowid / R_RUNS;
    int dropped = mask_dropped(maskp, cnts, (size_t)r * N_NODES + n);
    bf16x8 v;
    if (dropped) {
        #pragma unroll
        for (int j = 0; j < 8; ++j) v[j] = (bf16)0.0f;
    } else {
        v = *(const bf16x8*)(xb + (size_t)n * HID + c * 8);
    }
    *(bf16x8*)(h + (size_t)rowid * HID + c * 8) = v;
}

// level-0 pool, algebraic + LDS graph-slot pre-aggregation (batch sorted =>
// 32-node block spans few graphs; R13 lesson: each global atomic = ~32B HBM
// write, 1.28M of them = 40MB/91us; slots cut atomic count ~16x).
__global__ __launch_bounds__(256) void pool0_kernel(const bf16* __restrict__ xb,
                                                    const void* __restrict__ maskp,
                                                    const int* __restrict__ cnts,
                                                    const int* __restrict__ batch,
                                                    float* __restrict__ pooled) {
    __shared__ float lp[P0_SLOTS][64];
    __shared__ float lcnt[P0_NPB];
    __shared__ int gfirst;
    int tid = threadIdx.x;
    for (int i = tid; i < P0_SLOTS * 64; i += 256) ((float*)lp)[i] = 0.f;
    if (tid == 0) gfirst = batch[blockIdx.x * P0_NPB];
    if (tid < P0_NPB) {
        int n = blockIdx.x * P0_NPB + tid;
        int cnt = 0;
        #pragma unroll
        for (int r = 0; r < R_RUNS; ++r)
            cnt += !mask_dropped(maskp, cnts, (size_t)r * N_NODES + n);
        lcnt[tid] = (float)cnt * (1.0f / R_RUNS);
    }
    __syncthreads();
    int c = tid & 7, ln = tid >> 3;
    int n = blockIdx.x * P0_NPB + ln;
    bf16x8 xv = *(const bf16x8*)(xb + (size_t)n * HID + c * 8);
    float sc = lcnt[ln];
    int g = batch[n];
    int slot = g - gfirst;
    if (slot < P0_SLOTS) {
        #pragma unroll
        for (int j = 0; j < 8; ++j)
            atomicAdd(&lp[slot][c * 8 + j], (float)xv[j] * sc);
    } else {   // adversarial span: direct (rare)
        #pragma unroll
        for (int j = 0; j < 8; ++j)
            atomicAdd(&pooled[g * HID + c * 8 + j], (float)xv[j] * sc);
    }
    __syncthreads();
    for (int s = tid >> 6; s < P0_SLOTS; s += 4) {
        int f = tid & 63;
        float v = lp[s][f];
        if (v != 0.f) atomicAdd(&pooled[(gfirst + s) * HID + f], v);
    }
}

// ---------------- CSR build (keyed by dst) ----------------
__global__ void csr_count_kernel(const int* __restrict__ ei, int* __restrict__ deg) {
    int e = blockIdx.x * 256 + threadIdx.x;
    if (e < N_EDGES) atomicAdd(&deg[ei[N_EDGES + e]], 1);
}

__global__ void csr_scan_kernel(int* __restrict__ deg, int* __restrict__ row_start) {
    __shared__ int lds[1024];
    int tid = threadIdx.x;
    const int CH = 20;
    int base = tid * CH;
    int local[CH];
    int s = 0;
    #pragma unroll
    for (int j = 0; j < CH; ++j) {
        int n = base + j;
        int d = (n < N_NODES) ? deg[n] : 0;
        local[j] = d; s += d;
    }
    lds[tid] = s; __syncthreads();
    for (int off = 1; off < 1024; off <<= 1) {
        int add = (tid >= off) ? lds[tid - off] : 0;
        __syncthreads();
        lds[tid] += add;
        __syncthreads();
    }
    int excl = lds[tid] - s;
    #pragma unroll
    for (int j = 0; j < CH; ++j) {
        int n = base + j;
        if (n < N_NODES) { row_start[n] = excl; deg[n] = excl; excl += local[j]; }
    }
    if (tid == 1023) row_start[N_NODES] = lds[1023];
}

__global__ void csr_fill_kernel(const int* __restrict__ ei, int* __restrict__ cursor,
                                int* __restrict__ col) {
    int e = blockIdx.x * 256 + threadIdx.x;
    if (e < N_EDGES) {
        int src = ei[e];
        int dst = ei[N_EDGES + e];
        int pos = atomicAdd(&cursor[dst], 1);
        col[pos] = src;
    }
}

// ---------------- fused agg + gemm1: block = 8 nodes, 4-deep unroll
// (R12-exact, 87us measured; R13's 8-deep raised VGPR 52->72 and REGRESSED).
__global__ __launch_bounds__(256) void ag1_kernel(const uint32* __restrict__ hD,
                                                  const int* __restrict__ row_start,
                                                  const int* __restrict__ col,
                                                  const bf16* __restrict__ Wf,
                                                  const bf16* __restrict__ bias,
                                                  bf16* __restrict__ out,
                                                  float* __restrict__ statsOut) {
    __shared__ __align__(16) bf16 zT[AG_NPB * R_RUNS * TS];   // 80 x 72 = 11520 B
    __shared__ float lsum[64], lsq[64];
    uint32* zTu = (uint32*)zT;                                // row stride 36 dwords
    int tid = threadIdx.x;
    int wave = tid >> 6, lane = tid & 63, l16 = lane & 15, quad = lane >> 4;
    int b = blockIdx.x;
    const int NODE_DW = R_RUNS * HID / 2;   // 320

    if (tid < 64) { lsum[tid] = 0.f; lsq[tid] = 0.f; }

    for (int i = 0; i < AG_NPB / 4; ++i) {
        int nl = wave + 4 * i;
        int n = b * AG_NPB + nl;
        size_t base4 = (size_t)n * NODE_DW + lane * 4;
        size_t baset = (size_t)n * NODE_DW + 256 + lane;
        float acc[10];
        {
            uint4 u = *(const uint4*)(hD + base4);
            uint32 tw = hD[baset];
            acc[0] = __uint_as_float(u.x << 16); acc[1] = __uint_as_float(u.x & 0xFFFF0000u);
            acc[2] = __uint_as_float(u.y << 16); acc[3] = __uint_as_float(u.y & 0xFFFF0000u);
            acc[4] = __uint_as_float(u.z << 16); acc[5] = __uint_as_float(u.z & 0xFFFF0000u);
            acc[6] = __uint_as_float(u.w << 16); acc[7] = __uint_as_float(u.w & 0xFFFF0000u);
            acc[8] = __uint_as_float(tw << 16);  acc[9] = __uint_as_float(tw & 0xFFFF0000u);
        }
        int beg = row_start[n], end = row_start[n + 1];
        int idx = beg;
        for (; idx + 4 <= end; idx += 4) {
            uint4 a[4]; uint32 tw[4];
            #pragma unroll
            for (int u = 0; u < 4; ++u) {
                size_t o = (size_t)col[idx + u] * NODE_DW;
                a[u] = *(const uint4*)(hD + o + lane * 4);
                tw[u] = hD[o + 256 + lane];
            }
            #pragma unroll
            for (int u = 0; u < 4; ++u) {
                uint32 wd[4] = {a[u].x, a[u].y, a[u].z, a[u].w};
                #pragma unroll
                for (int c = 0; c < 4; ++c) {
                    acc[2 * c]     += __uint_as_float(wd[c] << 16);
                    acc[2 * c + 1] += __uint_as_float(wd[c] & 0xFFFF0000u);
                }
                acc[8] += __uint_as_float(tw[u] << 16);
                acc[9] += __uint_as_float(tw[u] & 0xFFFF0000u);
            }
        }
        for (; idx < end; ++idx) {
            size_t o = (size_t)col[idx] * NODE_DW;
            uint4 a0 = *(const uint4*)(hD + o + lane * 4);
            uint32 t0 = hD[o + 256 + lane];
            uint32 wd[4] = {a0.x, a0.y, a0.z, a0.w};
            #pragma unroll
            for (int c = 0; c < 4; ++c) {
                acc[2 * c]     += __uint_as_float(wd[c] << 16);
                acc[2 * c + 1] += __uint_as_float(wd[c] & 0xFFFF0000u);
            }
            acc[8] += __uint_as_float(t0 << 16);
            acc[9] += __uint_as_float(t0 & 0xFFFF0000u);
        }
        #pragma unroll
        for (int c = 0; c < 5; ++c) {
            int d = (c < 4) ? (lane * 4 + c) : (256 + lane);
            int rL = nl * R_RUNS + (d >> 5);
            int fp = d & 31;
            unsigned short lo = __builtin_bit_cast(unsigned short, (bf16)acc[2 * c]);
            unsigned short hi = __builtin_bit_cast(unsigned short, (bf16)acc[2 * c + 1]);
            zTu[rL * (TS / 2) + fp] = (uint32)lo | ((uint32)hi << 16);
        }
    }
    __syncthreads();

    bf16x8 bfr[4][2];
    #pragma unroll
    for (int nt = 0; nt < 4; ++nt)
        #pragma unroll
        for (int c = 0; c < 2; ++c)
            bfr[nt][c] = *(const bf16x8*)(Wf + (size_t)((nt * 2 + c) * 64 + lane) * 8);
    float bvs[4];
    #pragma unroll
    for (int nt = 0; nt < 4; ++nt) bvs[nt] = (float)bias[nt * 16 + l16];

    for (int g = wave; g < 5; g += 4) {
        const bf16* tp = &zT[(g * 16 + l16) * TS];
        bf16x8 a0 = *(const bf16x8*)(tp + quad * 8);
        bf16x8 a1 = *(const bf16x8*)(tp + 32 + quad * 8);
        f32x4 acc[4];
        #pragma unroll
        for (int nt = 0; nt < 4; ++nt) acc[nt] = (f32x4){bvs[nt], bvs[nt], bvs[nt], bvs[nt]};
        #pragma unroll
        for (int nt = 0; nt < 4; ++nt) {
            acc[nt] = __builtin_amdgcn_mfma_f32_16x16x32_bf16(a0, bfr[nt][0], acc[nt], 0, 0, 0);
            acc[nt] = __builtin_amdgcn_mfma_f32_16x16x32_bf16(a1, bfr[nt][1], acc[nt], 0, 0, 0);
        }
        size_t rowBase = (size_t)b * (AG_NPB * R_RUNS) + g * 16;
        #pragma unroll
        for (int nt = 0; nt < 4; ++nt) {
            float ss = 0.f, qq = 0.f;
            #pragma unroll
            for (int reg = 0; reg < 4; ++reg) {
                float v = acc[nt][reg];
                ss += v; qq += v * v;
                out[(rowBase + quad * 4 + reg) * HID + nt * 16 + l16] = (bf16)v;
            }
            atomicAdd(&lsum[nt * 16 + l16], ss);
            atomicAdd(&lsq[nt * 16 + l16], qq);
        }
    }
    __syncthreads();
    if (tid < 64) {
        int copy = b & (NCOPY - 1);
        atomicAdd(&statsOut[copy * 128 + tid], lsum[tid]);
        atomicAdd(&statsOut[copy * 128 + 64 + tid], lsq[tid]);
    }
}

// ---------------- gemm2: 320 rows/block (5 tiles of 64), grid 625 (R12-proven).
__global__ __launch_bounds__(256) void gemm64_kernel(const bf16* in,
                                                     const bf16* __restrict__ Wf,
                                                     const bf16* __restrict__ bias,
                                                     bf16* out,
                                                     const float* __restrict__ statsIn,
                                                     const bf16* __restrict__ gammaIn,
                                                     const bf16* __restrict__ betaIn,
                                                     float* __restrict__ statsOut) {
    __shared__ float lstat[128];
    __shared__ float lscale[64], lshift[64];
    __shared__ float lsum[64], lsq[64];
    int tid = threadIdx.x;
    int wave = tid >> 6, lane = tid & 63, l16 = lane & 15, quad = lane >> 4;

    if (tid < 128) {
        float s = 0.f;
        #pragma unroll
        for (int k = 0; k < NCOPY; ++k) s += statsIn[k * 128 + tid];
        lstat[tid] = s;
    }
    if (tid < 64) { lsum[tid] = 0.f; lsq[tid] = 0.f; }
    __syncthreads();
    if (tid < 64) {
        float mu = lstat[tid] * (1.0f / MROWS);
        float var = lstat[tid + 64] * (1.0f / MROWS) - mu * mu;
        float rs = rsqrtf(var + BN_EPS);
        float a = (float)gammaIn[tid] * rs;
        lscale[tid] = a;
        lshift[tid] = (float)betaIn[tid] - mu * a;
    }
    __syncthreads();

    bf16x8 bfrag[4][2];
    #pragma unroll
    for (int nt = 0; nt < 4; ++nt)
        #pragma unroll
        for (int c = 0; c < 2; ++c)
            bfrag[nt][c] = *(const bf16x8*)(Wf + (size_t)((nt * 2 + c) * 64 + lane) * 8);
    float bvs[4];
    #pragma unroll
    for (int nt = 0; nt < 4; ++nt) bvs[nt] = (float)bias[nt * 16 + l16];

    for (int t5 = 0; t5 < G2_TILES; ++t5) {
        size_t rowBase = (size_t)blockIdx.x * (G2_TILES * 64) + t5 * 64 + wave * 16;
        f32x4 acc[4];
        #pragma unroll
        for (int nt = 0; nt < 4; ++nt) acc[nt] = (f32x4){bvs[nt], bvs[nt], bvs[nt], bvs[nt]};

        size_t row = rowBase + l16;
        bf16x8 afrag[2];
        #pragma unroll
        for (int c = 0; c < 2; ++c) {
            int k0 = c * 32 + quad * 8;
            bf16x8 v = *(const bf16x8*)(in + row * HID + k0);
            #pragma unroll
            for (int j = 0; j < 8; ++j) {
                float f = (float)v[j] * lscale[k0 + j] + lshift[k0 + j];
                v[j] = (bf16)fmaxf(f, 0.f);
            }
            afrag[c] = v;
        }

        #pragma unroll
        for (int nt = 0; nt < 4; ++nt) {
            acc[nt] = __builtin_amdgcn_mfma_f32_16x16x32_bf16(afrag[0], bfrag[nt][0], acc[nt], 0, 0, 0);
            acc[nt] = __builtin_amdgcn_mfma_f32_16x16x32_bf16(afrag[1], bfrag[nt][1], acc[nt], 0, 0, 0);
        }

        #pragma unroll
        for (int nt = 0; nt < 4; ++nt) {
            float s = 0.f, q = 0.f;
            #pragma unroll
            for (int reg = 0; reg < 4; ++reg) {
                float v = acc[nt][reg];
                s += v; q += v * v;
                out[(rowBase + quad * 4 + reg) * HID + nt * 16 + l16] = (bf16)v;
            }
            atomicAdd(&lsum[nt * 16 + l16], s);
            atomicAdd(&lsq[nt * 16 + l16], q);
        }
    }
    __syncthreads();
    if (tid < 64) {
        int copy = blockIdx.x & (NCOPY - 1);
        atomicAdd(&statsOut[copy * 128 + tid], lsum[tid]);
        atomicAdd(&statsOut[copy * 128 + 64 + tid], lsq[tid]);
    }
}

// fused stats reduce + BN+ReLU + h-materialize + pool; LDS graph-slot
// pre-aggregation (sorted batch; fallback direct atomic if span > slots).
__global__ __launch_bounds__(256) void pool_bn_kernel(const bf16* __restrict__ t,
                                                      const float* __restrict__ statsIn,
                                                      const bf16* __restrict__ gammaIn,
                                                      const bf16* __restrict__ betaIn,
                                                      bf16* __restrict__ hOut,
                                                      const int* __restrict__ batch,
                                                      float* __restrict__ pooled) {
    __shared__ float lstat[128], lscale[64], lshift[64];
    __shared__ float lp[PB_SLOTS][64];
    __shared__ int gfirst;
    int tid = threadIdx.x;
    if (tid < 128) {
        float s = 0.f;
        #pragma unroll
        for (int k = 0; k < NCOPY; ++k) s += statsIn[k * 128 + tid];
        lstat[tid] = s;
    }
    for (int i = tid; i < PB_SLOTS * 64; i += 256) ((float*)lp)[i] = 0.f;
    if (tid == 0) gfirst = batch[blockIdx.x * PB_NPB];
    __syncthreads();
    if (tid < 64) {
        float mu = lstat[tid] * (1.0f / MROWS);
        float var = lstat[tid + 64] * (1.0f / MROWS) - mu * mu;
        float rs = rsqrtf(var + BN_EPS);
        float a = (float)gammaIn[tid] * rs;
        lscale[tid] = a;
        lshift[tid] = (float)betaIn[tid] - mu * a;
    }
    __syncthreads();
    int f = tid & 63, nsub = tid >> 6;
    float sc = lscale[f], sh = lshift[f];
    #pragma unroll
    for (int j = 0; j < PB_NPB / 4; ++j) {
        int n = blockIdx.x * PB_NPB + j * 4 + nsub;
        size_t base = (size_t)n * (R_RUNS * HID) + f;
        float s = 0.f;
        #pragma unroll
        for (int r = 0; r < R_RUNS; ++r) {
            float v = (float)t[base + r * HID];
            v = fmaxf(v * sc + sh, 0.f);
            hOut[base + r * HID] = (bf16)v;
            s += v;
        }
        int g = batch[n];
        int slot = g - gfirst;
        if (slot < PB_SLOTS) atomicAdd(&lp[slot][f], s * (1.0f / R_RUNS));
        else                 atomicAdd(&pooled[g * HID + f], s * (1.0f / R_RUNS));
    }
    __syncthreads();
    for (int s = tid >> 6; s < PB_SLOTS; s += 4) {
        float v = lp[s][tid & 63];
        if (v != 0.f) atomicAdd(&pooled[(gfirst + s) * HID + (tid & 63)], v);
    }
}

// final: out[g,:] = log_softmax( sum_l pooled5[l][g] @ fcw_l + fcb_l )
__global__ void fc_softmax_kernel(const float* __restrict__ pooled5,
                                  const bf16* __restrict__ params,
                                  const int* __restrict__ cnts, void* __restrict__ out) {
    int g = threadIdx.x;   // 128 threads
    if (g >= NG) return;
    float o[NC];
    #pragma unroll
    for (int c = 0; c < NC; ++c) o[c] = 0.f;
    for (int l = 0; l < NL + 1; ++l) {
        const float* pg = pooled5 + ((size_t)l * NG + g) * HID;
        const bf16* fw = params + PFW + l * (HID * NC);
        for (int k = 0; k < HID; ++k) {
            float p = pg[k];
            #pragma unroll
            for (int c = 0; c < NC; ++c) o[c] += p * (float)fw[k * NC + c];
        }
        #pragma unroll
        for (int c = 0; c < NC; ++c) o[c] += (float)params[PFB + l * NC + c];
    }
    float m = -1e30f;
    #pragma unroll
    for (int c = 0; c < NC; ++c) m = fmaxf(m, o[c]);
    float s = 0.f;
    #pragma unroll
    for (int c = 0; c < NC; ++c) s += expf(o[c] - m);
    float lg = logf(s);
    int f = cnts[0] > 64;
    #pragma unroll
    for (int c = 0; c < NC; ++c) {
        float val = o[c] - m - lg;
        if (f) ((float*)out)[g * NC + c] = val;
        else   ((bf16*)out)[g * NC + c] = (bf16)val;
    }
}

extern "C" void kernel_launch(void* const* d_in, const int* in_sizes, int n_in,
                              void* d_out, int out_size, void* d_ws, size_t ws_size,
                              hipStream_t stream) {
    const void* x     = d_in[0];
    const int*  ei    = (const int*)d_in[1];
    const int*  batch = (const int*)d_in[2];
    const void* maskp = d_in[3];

    char* ws = (char*)d_ws;
    int*   cnts    = (int*)(ws + OFF_FLAGS);
    int*   cursor  = (int*)(ws + OFF_CURSOR);
    float* statsb  = (float*)(ws + OFF_STATS);
    float* pooled5 = (float*)(ws + OFF_POOLED5);
    int*   rowst   = (int*)(ws + OFF_ROWST);
    int*   colbuf  = (int*)(ws + OFF_COL);
    bf16*  params  = (bf16*)(ws + OFF_PARAMS);
    bf16*  xb      = (bf16*)(ws + OFF_XB);
    bf16*  h       = (bf16*)(ws + OFF_H);
    bf16*  z       = (bf16*)(ws + OFF_Z);

    hipMemsetAsync(ws, 0, ZERO_BYTES, stream);   // flags+cursor+stats+pooled5

    detect_kernel<<<64, 256, 0, stream>>>((const unsigned short*)x,
                                          (const unsigned int*)maskp, cnts);
    convert_kernel<<<(CVT_TOT + 255) / 256, 256, 0, stream>>>(
        cnts, x, d_in[4], d_in[5], d_in[6], d_in[7], d_in[8], d_in[9], d_in[10],
        d_in[11], d_in[12], d_in[13], xb, params);

    csr_count_kernel<<<(N_EDGES + 255) / 256, 256, 0, stream>>>(ei, cursor);
    csr_scan_kernel<<<1, 1024, 0, stream>>>(cursor, rowst);
    csr_fill_kernel<<<(N_EDGES + 255) / 256, 256, 0, stream>>>(ei, cursor, colbuf);

    build_h0_kernel<<<(MROWS * 8) / 256, 256, 0, stream>>>(xb, maskp, cnts, h);
    pool0_kernel<<<N_NODES / P0_NPB, 256, 0, stream>>>(xb, maskp, cnts, batch, pooled5);

    for (int i = 0; i < NL; ++i) {
        float* st1 = statsb + (size_t)(2 * i) * (NCOPY * 128);
        float* st2 = statsb + (size_t)(2 * i + 1) * (NCOPY * 128);

        ag1_kernel<<<N_NODES / AG_NPB, 256, 0, stream>>>(
            (const uint32*)h, rowst, colbuf,
            params + PW1 + i * 4096, params + PB1 + i * 64, z, st1);

        gemm64_kernel<<<MROWS / (G2_TILES * 64), 256, 0, stream>>>(
            z, params + PW2 + i * 4096, params + PB2 + i * 64, z,
            st1, params + PG1 + i * 64, params + PBB1 + i * 64, st2);

        pool_bn_kernel<<<N_NODES / PB_NPB, 256, 0, stream>>>(
            z, st2, params + PG2 + i * 64, params + PBB2 + i * 64, h, batch,
            pooled5 + (size_t)(i + 1) * NG * HID);
    }

    fc_softmax_kernel<<<1, 128, 0, stream>>>(pooled5, params, cnts, d_out);
}

// Round 15
// 734.166 us; speedup vs baseline: 1.1708x; 1.0527x over previous
//
#include <hip/hip_runtime.h>

#define N_NODES 20000
#define N_EDGES 320000
#define R_RUNS 10
#define HID 64
#define NG 128
#define NC 10
#define NL 4
#define MROWS (R_RUNS * N_NODES)   // 200000
#define BN_EPS 1e-5f
#define NCOPY 16                   // stats copies per buffer
#define TS 72                      // LDS z-tile row stride (bf16 elems)
#define AG_NPB 8                   // ag1 nodes per block (R12-proven)
#define G2_TILES 5                 // gemm64 64-row tiles per block
#define PB_NPB 16                  // pool_bn nodes per block
#define PB_SLOTS 4                 // pool_bn LDS graph slots
#define P0_NPB 32                  // pool0 nodes per block
#define P0_SLOTS 6                 // pool0 LDS graph slots

typedef __bf16 bf16;
typedef __attribute__((ext_vector_type(8))) __bf16 bf16x8;
typedef __attribute__((ext_vector_type(4))) float f32x4;
typedef unsigned int uint32;

__device__ inline float blo(uint32 u) { return __uint_as_float(u << 16); }
__device__ inline float bhi(uint32 u) { return __uint_as_float(u & 0xFFFF0000u); }

// ---------------- workspace layout (bytes)
constexpr size_t OFF_FLAGS   = 0;          // int[4] counters, pad 256
constexpr size_t OFF_CURSOR  = 256;        // int[20001] -> pad 80384
constexpr size_t OFF_STATS   = 80640;      // f32[8 bufs][16 copies][128] = 65536
constexpr size_t OFF_POOLED5 = 146176;     // f32[5][128][64] = 163840
constexpr size_t ZERO_BYTES  = 310016;
constexpr size_t OFF_ROWST   = 310016;     // int[20001] -> pad 390400
constexpr size_t OFF_COL     = 390400;     // int[320000] -> 1670400
constexpr size_t OFF_KB      = 1670400;    // int[20000] 10-bit drop masks -> pad 1750528
constexpr size_t OFF_PARAMS  = 1750528;    // bf16[37554] -> pad 1825792
constexpr size_t OFF_XB      = 1825792;    // bf16[1280000] -> 4385792
constexpr size_t OFF_H       = 4385792;    // 25,600,000
constexpr size_t OFF_Z       = 29985792;   // 25,600,000 -> end 55,585,792

// params block element offsets (w1/w2 stored PRE-SWIZZLED in B-fragment order)
#define PW1  0
#define PB1  16384
#define PG1  16640
#define PBB1 16896
#define PW2  17152
#define PB2  33536
#define PG2  33792
#define PBB2 34048
#define PFW  34304
#define PFB  37504
#define PTOT 37554
#define CVT_TOT (1280000 + PTOT)

// ---------------- runtime dtype detection (validated R4-R14) ----------------
__global__ void detect_kernel(const unsigned short* __restrict__ xu,
                              const unsigned int* __restrict__ mw,
                              int* __restrict__ cnts) {
    int tid = blockIdx.x * 256 + threadIdx.x;   // 16384 threads
    int insane = 0, lowp = 0, f32w = 0, gt1 = 0;
    for (int i = tid; i < 4096; i += 16384) {
        unsigned int u = xu[2 * i];
        if (((u >> 7) & 0xFFu) >= 0x90u) insane++;
    }
    for (int i = tid; i < 50000; i += 16384) {
        unsigned int w = mw[i];
        if ((w & 0xFFFFu) == 0x3F80u) lowp = 1;
        else if (w == 0x3F800000u) f32w = 1;
        else if (w > 1u) gt1 = 1;
    }
    if (insane) atomicAdd(&cnts[0], insane);
    if (lowp)   atomicOr(&cnts[1], 1);
    if (f32w)   atomicOr(&cnts[2], 1);
    if (gt1)    atomicOr(&cnts[3], 1);
}

__device__ inline bf16 ld_any(const void* p, int i, int f32mode) {
    if (f32mode) return (bf16)((const float*)p)[i];
    return ((const bf16*)p)[i];
}

__device__ inline int mask_dropped(const void* maskp, const int* cnts, size_t idx) {
    int w = cnts[1] ? 2 : (cnts[2] ? 4 : (cnts[3] ? 1 : 4));
    if (w == 1) return ((const unsigned char*)maskp)[idx] != 0;
    if (w == 2) return ((const unsigned short*)maskp)[idx] != 0;
    return ((const unsigned int*)maskp)[idx] != 0;
}

// convert all float inputs to canonical bf16; w1/w2 written in per-lane
// B-fragment order:
//   Wf[((nt*2+c)*64 + lane)*8 + j] = W[(c*32+(lane>>4)*8+j)*64 + nt*16+(lane&15)]
__global__ void convert_kernel(const int* __restrict__ cnts,
                               const void* x, const void* w1, const void* b1,
                               const void* g1, const void* bb1, const void* w2,
                               const void* b2, const void* g2, const void* bb2,
                               const void* fw, const void* fb,
                               bf16* __restrict__ xb, bf16* __restrict__ params) {
    int t = blockIdx.x * 256 + threadIdx.x;
    if (t >= CVT_TOT) return;
    int f = cnts[0] > 64;
    if (t < 1280000) { xb[t] = ld_any(x, t, f); return; }
    int u = t - 1280000;
    if (u < PB1 || (u >= PW2 && u < PB2)) {       // swizzled weight regions
        const void* src = (u < PB1) ? w1 : w2;
        int v = (u < PB1) ? u : u - PW2;
        int layer = v >> 12, rem = v & 4095;
        int j = rem & 7, lane = (rem >> 3) & 63, ntc = rem >> 9;
        int nt = ntc >> 1, c = ntc & 1;
        int k = c * 32 + (lane >> 4) * 8 + j;
        int n = nt * 16 + (lane & 15);
        params[u] = ld_any(src, layer * 4096 + k * 64 + n, f);
        return;
    }
    const void* src; int base;
    if      (u < PG1)  { src = b1;  base = PB1; }
    else if (u < PBB1) { src = g1;  base = PG1; }
    else if (u < PW2)  { src = bb1; base = PBB1; }
    else if (u < PG2)  { src = b2;  base = PB2; }
    else if (u < PBB2) { src = g2;  base = PG2; }
    else if (u < PFW)  { src = bb2; base = PBB2; }
    else if (u < PFB)  { src = fw;  base = PFW; }
    else               { src = fb;  base = PFB; }
    params[u] = ld_any(src, u - base, f);
}

// level-0 pool (algebraic, LDS graph slots) + pack 10-bit drop masks kb[n].
__global__ __launch_bounds__(256) void pool0_kernel(const bf16* __restrict__ xb,
                                                    const void* __restrict__ maskp,
                                                    const int* __restrict__ cnts,
                                                    const int* __restrict__ batch,
                                                    float* __restrict__ pooled,
                                                    int* __restrict__ kb) {
    __shared__ float lp[P0_SLOTS][64];
    __shared__ float lcnt[P0_NPB];
    __shared__ int gfirst;
    int tid = threadIdx.x;
    for (int i = tid; i < P0_SLOTS * 64; i += 256) ((float*)lp)[i] = 0.f;
    if (tid == 0) gfirst = batch[blockIdx.x * P0_NPB];
    if (tid < P0_NPB) {
        int n = blockIdx.x * P0_NPB + tid;
        int cnt = 0, kbv = 0;
        #pragma unroll
        for (int r = 0; r < R_RUNS; ++r) {
            int d = mask_dropped(maskp, cnts, (size_t)r * N_NODES + n);
            kbv |= d << r;
            cnt += !d;
        }
        lcnt[tid] = (float)cnt * (1.0f / R_RUNS);
        kb[n] = kbv;
    }
    __syncthreads();
    int c = tid & 7, ln = tid >> 3;
    int n = blockIdx.x * P0_NPB + ln;
    bf16x8 xv = *(const bf16x8*)(xb + (size_t)n * HID + c * 8);
    float sc = lcnt[ln];
    int g = batch[n];
    int slot = g - gfirst;
    if (slot < P0_SLOTS) {
        #pragma unroll
        for (int j = 0; j < 8; ++j)
            atomicAdd(&lp[slot][c * 8 + j], (float)xv[j] * sc);
    } else {
        #pragma unroll
        for (int j = 0; j < 8; ++j)
            atomicAdd(&pooled[g * HID + c * 8 + j], (float)xv[j] * sc);
    }
    __syncthreads();
    for (int s = tid >> 6; s < P0_SLOTS; s += 4) {
        int f = tid & 63;
        float v = lp[s][f];
        if (v != 0.f) atomicAdd(&pooled[(gfirst + s) * HID + f], v);
    }
}

// ---------------- CSR build (keyed by dst) ----------------
__global__ void csr_count_kernel(const int* __restrict__ ei, int* __restrict__ deg) {
    int e = blockIdx.x * 256 + threadIdx.x;
    if (e < N_EDGES) atomicAdd(&deg[ei[N_EDGES + e]], 1);
}

__global__ void csr_scan_kernel(int* __restrict__ deg, int* __restrict__ row_start) {
    __shared__ int lds[1024];
    int tid = threadIdx.x;
    const int CH = 20;
    int base = tid * CH;
    int local[CH];
    int s = 0;
    #pragma unroll
    for (int j = 0; j < CH; ++j) {
        int n = base + j;
        int d = (n < N_NODES) ? deg[n] : 0;
        local[j] = d; s += d;
    }
    lds[tid] = s; __syncthreads();
    for (int off = 1; off < 1024; off <<= 1) {
        int add = (tid >= off) ? lds[tid - off] : 0;
        __syncthreads();
        lds[tid] += add;
        __syncthreads();
    }
    int excl = lds[tid] - s;
    #pragma unroll
    for (int j = 0; j < CH; ++j) {
        int n = base + j;
        if (n < N_NODES) { row_start[n] = excl; deg[n] = excl; excl += local[j]; }
    }
    if (tid == 1023) row_start[N_NODES] = lds[1023];
}

__global__ void csr_fill_kernel(const int* __restrict__ ei, int* __restrict__ cursor,
                                int* __restrict__ col) {
    int e = blockIdx.x * 256 + threadIdx.x;
    if (e < N_EDGES) {
        int src = ei[e];
        int dst = ei[N_EDGES + e];
        int pos = atomicAdd(&cursor[dst], 1);
        col[pos] = src;
    }
}

// ---------------- LAYER-1 fused agg+gemm1: h0 never materialized.
// z[r,n] = keep[r][n]*x[n] + sum_j keep[r][j]*x[j]; per neighbor we read the
// 128B x row (L2-resident, 2.5MB) + 10-bit kb mask instead of 1280B of h0.
// Lane = feature pair (p=lane&31); half-waves split the neighbor list, then
// __shfl_xor(32) combines. Phase 2 = ag1's proven LDS gemm.
__global__ __launch_bounds__(256) void ag1_l1_kernel(const uint32* __restrict__ xbD,
                                                     const int* __restrict__ kb,
                                                     const int* __restrict__ row_start,
                                                     const int* __restrict__ col,
                                                     const bf16* __restrict__ Wf,
                                                     const bf16* __restrict__ bias,
                                                     bf16* __restrict__ out,
                                                     float* __restrict__ statsOut) {
    __shared__ __align__(16) bf16 zT[AG_NPB * R_RUNS * TS];
    __shared__ float lsum[64], lsq[64];
    uint32* zTu = (uint32*)zT;
    int tid = threadIdx.x;
    int wave = tid >> 6, lane = tid & 63, l16 = lane & 15, quad = lane >> 4;
    int p = lane & 31, hf = lane >> 5;
    int b = blockIdx.x;

    if (tid < 64) { lsum[tid] = 0.f; lsq[tid] = 0.f; }

    for (int i = 0; i < AG_NPB / 4; ++i) {
        int nl = wave + 4 * i;
        int n = b * AG_NPB + nl;
        float ax[R_RUNS], ay[R_RUNS];
        {   // self term (half 0 only; half 1 contributes 0)
            uint32 xs = xbD[(size_t)n * 32 + p];
            int ms = kb[n];
            float fx = blo(xs), fy = bhi(xs);
            #pragma unroll
            for (int r = 0; r < R_RUNS; ++r) {
                int keep = (hf == 0) && !((ms >> r) & 1);
                ax[r] = keep ? fx : 0.f;
                ay[r] = keep ? fy : 0.f;
            }
        }
        int beg = row_start[n], end = row_start[n + 1];
        int iters = (end - beg + 1) >> 1;   // per-half ceiling
        int k = 0;
        for (; k + 4 <= iters; k += 4) {
            uint32 xv[4]; int mv[4];
            #pragma unroll
            for (int u = 0; u < 4; ++u) {
                int idx = beg + 2 * (k + u) + hf;
                int valid = idx < end;
                int j = valid ? col[idx] : n;
                xv[u] = xbD[(size_t)j * 32 + p];
                mv[u] = valid ? kb[j] : 0x3FF;
            }
            #pragma unroll
            for (int u = 0; u < 4; ++u) {
                float fx = blo(xv[u]), fy = bhi(xv[u]);
                #pragma unroll
                for (int r = 0; r < R_RUNS; ++r)
                    if (!((mv[u] >> r) & 1)) { ax[r] += fx; ay[r] += fy; }
            }
        }
        for (; k < iters; ++k) {
            int idx = beg + 2 * k + hf;
            int valid = idx < end;
            int j = valid ? col[idx] : n;
            uint32 xv = xbD[(size_t)j * 32 + p];
            int mv = valid ? kb[j] : 0x3FF;
            float fx = blo(xv), fy = bhi(xv);
            #pragma unroll
            for (int r = 0; r < R_RUNS; ++r)
                if (!((mv >> r) & 1)) { ax[r] += fx; ay[r] += fy; }
        }
        // combine halves
        #pragma unroll
        for (int r = 0; r < R_RUNS; ++r) {
            ax[r] += __shfl_xor(ax[r], 32);
            ay[r] += __shfl_xor(ay[r], 32);
        }
        // write 5 runs per half to the LDS tile
        #pragma unroll
        for (int q = 0; q < 5; ++q) {
            int r = hf * 5 + q;
            unsigned short lo = __builtin_bit_cast(unsigned short, (bf16)ax[r]);
            unsigned short hi = __builtin_bit_cast(unsigned short, (bf16)ay[r]);
            zTu[(nl * R_RUNS + r) * (TS / 2) + p] = (uint32)lo | ((uint32)hi << 16);
        }
    }
    __syncthreads();

    // ---- phase 2: gemm1 from LDS (ag1-identical)
    bf16x8 bfr[4][2];
    #pragma unroll
    for (int nt = 0; nt < 4; ++nt)
        #pragma unroll
        for (int c = 0; c < 2; ++c)
            bfr[nt][c] = *(const bf16x8*)(Wf + (size_t)((nt * 2 + c) * 64 + lane) * 8);
    float bvs[4];
    #pragma unroll
    for (int nt = 0; nt < 4; ++nt) bvs[nt] = (float)bias[nt * 16 + l16];

    for (int g = wave; g < 5; g += 4) {
        const bf16* tp = &zT[(g * 16 + l16) * TS];
        bf16x8 a0 = *(const bf16x8*)(tp + quad * 8);
        bf16x8 a1 = *(const bf16x8*)(tp + 32 + quad * 8);
        f32x4 acc[4];
        #pragma unroll
        for (int nt = 0; nt < 4; ++nt) acc[nt] = (f32x4){bvs[nt], bvs[nt], bvs[nt], bvs[nt]};
        #pragma unroll
        for (int nt = 0; nt < 4; ++nt) {
            acc[nt] = __builtin_amdgcn_mfma_f32_16x16x32_bf16(a0, bfr[nt][0], acc[nt], 0, 0, 0);
            acc[nt] = __builtin_amdgcn_mfma_f32_16x16x32_bf16(a1, bfr[nt][1], acc[nt], 0, 0, 0);
        }
        size_t rowBase = (size_t)b * (AG_NPB * R_RUNS) + g * 16;
        #pragma unroll
        for (int nt = 0; nt < 4; ++nt) {
            float ss = 0.f, qq = 0.f;
            #pragma unroll
            for (int reg = 0; reg < 4; ++reg) {
                float v = acc[nt][reg];
                ss += v; qq += v * v;
                out[(rowBase + quad * 4 + reg) * HID + nt * 16 + l16] = (bf16)v;
            }
            atomicAdd(&lsum[nt * 16 + l16], ss);
            atomicAdd(&lsq[nt * 16 + l16], qq);
        }
    }
    __syncthreads();
    if (tid < 64) {
        int copy = b & (NCOPY - 1);
        atomicAdd(&statsOut[copy * 128 + tid], lsum[tid]);
        atomicAdd(&statsOut[copy * 128 + 64 + tid], lsq[tid]);
    }
}

// ---------------- layers 2-4 fused agg + gemm1 (R12/R14-proven, 87us).
__global__ __launch_bounds__(256) void ag1_kernel(const uint32* __restrict__ hD,
                                                  const int* __restrict__ row_start,
                                                  const int* __restrict__ col,
                                                  const bf16* __restrict__ Wf,
                                                  const bf16* __restrict__ bias,
                                                  bf16* __restrict__ out,
                                                  float* __restrict__ statsOut) {
    __shared__ __align__(16) bf16 zT[AG_NPB * R_RUNS * TS];   // 80 x 72 = 11520 B
    __shared__ float lsum[64], lsq[64];
    uint32* zTu = (uint32*)zT;                                // row stride 36 dwords
    int tid = threadIdx.x;
    int wave = tid >> 6, lane = tid & 63, l16 = lane & 15, quad = lane >> 4;
    int b = blockIdx.x;
    const int NODE_DW = R_RUNS * HID / 2;   // 320

    if (tid < 64) { lsum[tid] = 0.f; lsq[tid] = 0.f; }

    for (int i = 0; i < AG_NPB / 4; ++i) {
        int nl = wave + 4 * i;
        int n = b * AG_NPB + nl;
        size_t base4 = (size_t)n * NODE_DW + lane * 4;
        size_t baset = (size_t)n * NODE_DW + 256 + lane;
        float acc[10];
        {
            uint4 u = *(const uint4*)(hD + base4);
            uint32 tw = hD[baset];
            acc[0] = blo(u.x); acc[1] = bhi(u.x);
            acc[2] = blo(u.y); acc[3] = bhi(u.y);
            acc[4] = blo(u.z); acc[5] = bhi(u.z);
            acc[6] = blo(u.w); acc[7] = bhi(u.w);
            acc[8] = blo(tw);  acc[9] = bhi(tw);
        }
        int beg = row_start[n], end = row_start[n + 1];
        int idx = beg;
        for (; idx + 4 <= end; idx += 4) {
            uint4 a[4]; uint32 tw[4];
            #pragma unroll
            for (int u = 0; u < 4; ++u) {
                size_t o = (size_t)col[idx + u] * NODE_DW;
                a[u] = *(const uint4*)(hD + o + lane * 4);
                tw[u] = hD[o + 256 + lane];
            }
            #pragma unroll
            for (int u = 0; u < 4; ++u) {
                uint32 wd[4] = {a[u].x, a[u].y, a[u].z, a[u].w};
                #pragma unroll
                for (int c = 0; c < 4; ++c) {
                    acc[2 * c]     += blo(wd[c]);
                    acc[2 * c + 1] += bhi(wd[c]);
                }
                acc[8] += blo(tw[u]);
                acc[9] += bhi(tw[u]);
            }
        }
        for (; idx < end; ++idx) {
            size_t o = (size_t)col[idx] * NODE_DW;
            uint4 a0 = *(const uint4*)(hD + o + lane * 4);
            uint32 t0 = hD[o + 256 + lane];
            uint32 wd[4] = {a0.x, a0.y, a0.z, a0.w};
            #pragma unroll
            for (int c = 0; c < 4; ++c) {
                acc[2 * c]     += blo(wd[c]);
                acc[2 * c + 1] += bhi(wd[c]);
            }
            acc[8] += blo(t0);
            acc[9] += bhi(t0);
        }
        #pragma unroll
        for (int c = 0; c < 5; ++c) {
            int d = (c < 4) ? (lane * 4 + c) : (256 + lane);
            int rL = nl * R_RUNS + (d >> 5);
            int fp = d & 31;
            unsigned short lo = __builtin_bit_cast(unsigned short, (bf16)acc[2 * c]);
            unsigned short hi = __builtin_bit_cast(unsigned short, (bf16)acc[2 * c + 1]);
            zTu[rL * (TS / 2) + fp] = (uint32)lo | ((uint32)hi << 16);
        }
    }
    __syncthreads();

    bf16x8 bfr[4][2];
    #pragma unroll
    for (int nt = 0; nt < 4; ++nt)
        #pragma unroll
        for (int c = 0; c < 2; ++c)
            bfr[nt][c] = *(const bf16x8*)(Wf + (size_t)((nt * 2 + c) * 64 + lane) * 8);
    float bvs[4];
    #pragma unroll
    for (int nt = 0; nt < 4; ++nt) bvs[nt] = (float)bias[nt * 16 + l16];

    for (int g = wave; g < 5; g += 4) {
        const bf16* tp = &zT[(g * 16 + l16) * TS];
        bf16x8 a0 = *(const bf16x8*)(tp + quad * 8);
        bf16x8 a1 = *(const bf16x8*)(tp + 32 + quad * 8);
        f32x4 acc[4];
        #pragma unroll
        for (int nt = 0; nt < 4; ++nt) acc[nt] = (f32x4){bvs[nt], bvs[nt], bvs[nt], bvs[nt]};
        #pragma unroll
        for (int nt = 0; nt < 4; ++nt) {
            acc[nt] = __builtin_amdgcn_mfma_f32_16x16x32_bf16(a0, bfr[nt][0], acc[nt], 0, 0, 0);
            acc[nt] = __builtin_amdgcn_mfma_f32_16x16x32_bf16(a1, bfr[nt][1], acc[nt], 0, 0, 0);
        }
        size_t rowBase = (size_t)b * (AG_NPB * R_RUNS) + g * 16;
        #pragma unroll
        for (int nt = 0; nt < 4; ++nt) {
            float ss = 0.f, qq = 0.f;
            #pragma unroll
            for (int reg = 0; reg < 4; ++reg) {
                float v = acc[nt][reg];
                ss += v; qq += v * v;
                out[(rowBase + quad * 4 + reg) * HID + nt * 16 + l16] = (bf16)v;
            }
            atomicAdd(&lsum[nt * 16 + l16], ss);
            atomicAdd(&lsq[nt * 16 + l16], qq);
        }
    }
    __syncthreads();
    if (tid < 64) {
        int copy = b & (NCOPY - 1);
        atomicAdd(&statsOut[copy * 128 + tid], lsum[tid]);
        atomicAdd(&statsOut[copy * 128 + 64 + tid], lsq[tid]);
    }
}

// ---------------- gemm2: 320 rows/block (5 tiles of 64), grid 625 (R12-proven).
__global__ __launch_bounds__(256) void gemm64_kernel(const bf16* in,
                                                     const bf16* __restrict__ Wf,
                                                     const bf16* __restrict__ bias,
                                                     bf16* out,
                                                     const float* __restrict__ statsIn,
                                                     const bf16* __restrict__ gammaIn,
                                                     const bf16* __restrict__ betaIn,
                                                     float* __restrict__ statsOut) {
    __shared__ float lstat[128];
    __shared__ float lscale[64], lshift[64];
    __shared__ float lsum[64], lsq[64];
    int tid = threadIdx.x;
    int wave = tid >> 6, lane = tid & 63, l16 = lane & 15, quad = lane >> 4;

    if (tid < 128) {
        float s = 0.f;
        #pragma unroll
        for (int k = 0; k < NCOPY; ++k) s += statsIn[k * 128 + tid];
        lstat[tid] = s;
    }
    if (tid < 64) { lsum[tid] = 0.f; lsq[tid] = 0.f; }
    __syncthreads();
    if (tid < 64) {
        float mu = lstat[tid] * (1.0f / MROWS);
        float var = lstat[tid + 64] * (1.0f / MROWS) - mu * mu;
        float rs = rsqrtf(var + BN_EPS);
        float a = (float)gammaIn[tid] * rs;
        lscale[tid] = a;
        lshift[tid] = (float)betaIn[tid] - mu * a;
    }
    __syncthreads();

    bf16x8 bfrag[4][2];
    #pragma unroll
    for (int nt = 0; nt < 4; ++nt)
        #pragma unroll
        for (int c = 0; c < 2; ++c)
            bfrag[nt][c] = *(const bf16x8*)(Wf + (size_t)((nt * 2 + c) * 64 + lane) * 8);
    float bvs[4];
    #pragma unroll
    for (int nt = 0; nt < 4; ++nt) bvs[nt] = (float)bias[nt * 16 + l16];

    for (int t5 = 0; t5 < G2_TILES; ++t5) {
        size_t rowBase = (size_t)blockIdx.x * (G2_TILES * 64) + t5 * 64 + wave * 16;
        f32x4 acc[4];
        #pragma unroll
        for (int nt = 0; nt < 4; ++nt) acc[nt] = (f32x4){bvs[nt], bvs[nt], bvs[nt], bvs[nt]};

        size_t row = rowBase + l16;
        bf16x8 afrag[2];
        #pragma unroll
        for (int c = 0; c < 2; ++c) {
            int k0 = c * 32 + quad * 8;
            bf16x8 v = *(const bf16x8*)(in + row * HID + k0);
            #pragma unroll
            for (int j = 0; j < 8; ++j) {
                float f = (float)v[j] * lscale[k0 + j] + lshift[k0 + j];
                v[j] = (bf16)fmaxf(f, 0.f);
            }
            afrag[c] = v;
        }

        #pragma unroll
        for (int nt = 0; nt < 4; ++nt) {
            acc[nt] = __builtin_amdgcn_mfma_f32_16x16x32_bf16(afrag[0], bfrag[nt][0], acc[nt], 0, 0, 0);
            acc[nt] = __builtin_amdgcn_mfma_f32_16x16x32_bf16(afrag[1], bfrag[nt][1], acc[nt], 0, 0, 0);
        }

        #pragma unroll
        for (int nt = 0; nt < 4; ++nt) {
            float s = 0.f, q = 0.f;
            #pragma unroll
            for (int reg = 0; reg < 4; ++reg) {
                float v = acc[nt][reg];
                s += v; q += v * v;
                out[(rowBase + quad * 4 + reg) * HID + nt * 16 + l16] = (bf16)v;
            }
            atomicAdd(&lsum[nt * 16 + l16], s);
            atomicAdd(&lsq[nt * 16 + l16], q);
        }
    }
    __syncthreads();
    if (tid < 64) {
        int copy = blockIdx.x & (NCOPY - 1);
        atomicAdd(&statsOut[copy * 128 + tid], lsum[tid]);
        atomicAdd(&statsOut[copy * 128 + 64 + tid], lsq[tid]);
    }
}

// fused stats reduce + BN+ReLU + h-materialize + pool (R14 form).
__global__ __launch_bounds__(256) void pool_bn_kernel(const bf16* __restrict__ t,
                                                      const float* __restrict__ statsIn,
                                                      const bf16* __restrict__ gammaIn,
                                                      const bf16* __restrict__ betaIn,
                                                      bf16* __restrict__ hOut,
                                                      const int* __restrict__ batch,
                                                      float* __restrict__ pooled) {
    __shared__ float lstat[128], lscale[64], lshift[64];
    __shared__ float lp[PB_SLOTS][64];
    __shared__ int gfirst;
    int tid = threadIdx.x;
    if (tid < 128) {
        float s = 0.f;
        #pragma unroll
        for (int k = 0; k < NCOPY; ++k) s += statsIn[k * 128 + tid];
        lstat[tid] = s;
    }
    for (int i = tid; i < PB_SLOTS * 64; i += 256) ((float*)lp)[i] = 0.f;
    if (tid == 0) gfirst = batch[blockIdx.x * PB_NPB];
    __syncthreads();
    if (tid < 64) {
        float mu = lstat[tid] * (1.0f / MROWS);
        float var = lstat[tid + 64] * (1.0f / MROWS) - mu * mu;
        float rs = rsqrtf(var + BN_EPS);
        float a = (float)gammaIn[tid] * rs;
        lscale[tid] = a;
        lshift[tid] = (float)betaIn[tid] - mu * a;
    }
    __syncthreads();
    int f = tid & 63, nsub = tid >> 6;
    float sc = lscale[f], sh = lshift[f];
    #pragma unroll
    for (int j = 0; j < PB_NPB / 4; ++j) {
        int n = blockIdx.x * PB_NPB + j * 4 + nsub;
        size_t base = (size_t)n * (R_RUNS * HID) + f;
        float s = 0.f;
        #pragma unroll
        for (int r = 0; r < R_RUNS; ++r) {
            float v = (float)t[base + r * HID];
            v = fmaxf(v * sc + sh, 0.f);
            hOut[base + r * HID] = (bf16)v;
            s += v;
        }
        int g = batch[n];
        int slot = g - gfirst;
        if (slot < PB_SLOTS) atomicAdd(&lp[slot][f], s * (1.0f / R_RUNS));
        else                 atomicAdd(&pooled[g * HID + f], s * (1.0f / R_RUNS));
    }
    __syncthreads();
    for (int s = tid >> 6; s < PB_SLOTS; s += 4) {
        float v = lp[s][tid & 63];
        if (v != 0.f) atomicAdd(&pooled[(gfirst + s) * HID + (tid & 63)], v);
    }
}

// final: out[g,:] = log_softmax( sum_l pooled5[l][g] @ fcw_l + fcb_l )
__global__ void fc_softmax_kernel(const float* __restrict__ pooled5,
                                  const bf16* __restrict__ params,
                                  const int* __restrict__ cnts, void* __restrict__ out) {
    int g = threadIdx.x;   // 128 threads
    if (g >= NG) return;
    float o[NC];
    #pragma unroll
    for (int c = 0; c < NC; ++c) o[c] = 0.f;
    for (int l = 0; l < NL + 1; ++l) {
        const float* pg = pooled5 + ((size_t)l * NG + g) * HID;
        const bf16* fw = params + PFW + l * (HID * NC);
        for (int k = 0; k < HID; ++k) {
            float p = pg[k];
            #pragma unroll
            for (int c = 0; c < NC; ++c) o[c] += p * (float)fw[k * NC + c];
        }
        #pragma unroll
        for (int c = 0; c < NC; ++c) o[c] += (float)params[PFB + l * NC + c];
    }
    float m = -1e30f;
    #pragma unroll
    for (int c = 0; c < NC; ++c) m = fmaxf(m, o[c]);
    float s = 0.f;
    #pragma unroll
    for (int c = 0; c < NC; ++c) s += expf(o[c] - m);
    float lg = logf(s);
    int f = cnts[0] > 64;
    #pragma unroll
    for (int c = 0; c < NC; ++c) {
        float val = o[c] - m - lg;
        if (f) ((float*)out)[g * NC + c] = val;
        else   ((bf16*)out)[g * NC + c] = (bf16)val;
    }
}

extern "C" void kernel_launch(void* const* d_in, const int* in_sizes, int n_in,
                              void* d_out, int out_size, void* d_ws, size_t ws_size,
                              hipStream_t stream) {
    const void* x     = d_in[0];
    const int*  ei    = (const int*)d_in[1];
    const int*  batch = (const int*)d_in[2];
    const void* maskp = d_in[3];

    char* ws = (char*)d_ws;
    int*   cnts    = (int*)(ws + OFF_FLAGS);
    int*   cursor  = (int*)(ws + OFF_CURSOR);
    float* statsb  = (float*)(ws + OFF_STATS);
    float* pooled5 = (float*)(ws + OFF_POOLED5);
    int*   rowst   = (int*)(ws + OFF_ROWST);
    int*   colbuf  = (int*)(ws + OFF_COL);
    int*   kbuf    = (int*)(ws + OFF_KB);
    bf16*  params  = (bf16*)(ws + OFF_PARAMS);
    bf16*  xb      = (bf16*)(ws + OFF_XB);
    bf16*  h       = (bf16*)(ws + OFF_H);
    bf16*  z       = (bf16*)(ws + OFF_Z);

    hipMemsetAsync(ws, 0, ZERO_BYTES, stream);   // flags+cursor+stats+pooled5

    detect_kernel<<<64, 256, 0, stream>>>((const unsigned short*)x,
                                          (const unsigned int*)maskp, cnts);
    convert_kernel<<<(CVT_TOT + 255) / 256, 256, 0, stream>>>(
        cnts, x, d_in[4], d_in[5], d_in[6], d_in[7], d_in[8], d_in[9], d_in[10],
        d_in[11], d_in[12], d_in[13], xb, params);

    csr_count_kernel<<<(N_EDGES + 255) / 256, 256, 0, stream>>>(ei, cursor);
    csr_scan_kernel<<<1, 1024, 0, stream>>>(cursor, rowst);
    csr_fill_kernel<<<(N_EDGES + 255) / 256, 256, 0, stream>>>(ei, cursor, colbuf);

    pool0_kernel<<<N_NODES / P0_NPB, 256, 0, stream>>>(xb, maskp, cnts, batch,
                                                       pooled5, kbuf);

    for (int i = 0; i < NL; ++i) {
        float* st1 = statsb + (size_t)(2 * i) * (NCOPY * 128);
        float* st2 = statsb + (size_t)(2 * i + 1) * (NCOPY * 128);

        if (i == 0) {
            ag1_l1_kernel<<<N_NODES / AG_NPB, 256, 0, stream>>>(
                (const uint32*)xb, kbuf, rowst, colbuf,
                params + PW1, params + PB1, z, st1);
        } else {
            ag1_kernel<<<N_NODES / AG_NPB, 256, 0, stream>>>(
                (const uint32*)h, rowst, colbuf,
                params + PW1 + i * 4096, params + PB1 + i * 64, z, st1);
        }

        gemm64_kernel<<<MROWS / (G2_TILES * 64), 256, 0, stream>>>(
            z, params + PW2 + i * 4096, params + PB2 + i * 64, z,
            st1, params + PG1 + i * 64, params + PBB1 + i * 64, st2);

        pool_bn_kernel<<<N_NODES / PB_NPB, 256, 0, stream>>>(
            z, st2, params + PG2 + i * 64, params + PBB2 + i * 64, h, batch,
            pooled5 + (size_t)(i + 1) * NG * HID);
    }

    fc_softmax_kernel<<<1, 128, 0, stream>>>(pooled5, params, cnts, d_out);
}

// Round 16
// 730.729 us; speedup vs baseline: 1.1763x; 1.0047x over previous
//
#include <hip/hip_runtime.h>

#define N_NODES 20000
#define N_EDGES 320000
#define R_RUNS 10
#define HID 64
#define NG 128
#define NC 10
#define NL 4
#define MROWS (R_RUNS * N_NODES)   // 200000
#define BN_EPS 1e-5f
#define NCOPY 16                   // stats copies per buffer
#define TS 72                      // LDS z-tile row stride (bf16 elems)
#define AG_NPB 8                   // ag1 nodes per block
#define G2_TILES 5                 // gemm64 64-row tiles per block
#define PB_NPB 16                  // pool_bn nodes per block
#define PB_SLOTS 4                 // pool_bn LDS graph slots
#define P0_NPB 32                  // pool0 nodes per block
#define P0_SLOTS 6                 // pool0 LDS graph slots

typedef __bf16 bf16;
typedef __attribute__((ext_vector_type(8))) __bf16 bf16x8;
typedef __attribute__((ext_vector_type(4))) float f32x4;
typedef unsigned int uint32;

__device__ inline float blo(uint32 u) { return __uint_as_float(u << 16); }
__device__ inline float bhi(uint32 u) { return __uint_as_float(u & 0xFFFF0000u); }

// ---------------- workspace layout (bytes)
constexpr size_t OFF_FLAGS   = 0;          // int[4] counters, pad 256
constexpr size_t OFF_CURSOR  = 256;        // int[20001] -> pad 80384
constexpr size_t OFF_STATS   = 80640;      // f32[8 bufs][16 copies][128] = 65536
constexpr size_t OFF_POOLED5 = 146176;     // f32[5][128][64] = 163840
constexpr size_t ZERO_BYTES  = 310016;
constexpr size_t OFF_ROWST   = 310016;     // int[20001] -> pad 390400
constexpr size_t OFF_COL     = 390400;     // int[320000] -> 1670400
constexpr size_t OFF_KB      = 1670400;    // int[20000] 10-bit drop masks -> pad 1750528
constexpr size_t OFF_PARAMS  = 1750528;    // bf16[37554] -> pad 1825792
constexpr size_t OFF_XB      = 1825792;    // bf16[1280000] -> 4385792
constexpr size_t OFF_H       = 4385792;    // 25,600,000
constexpr size_t OFF_Z       = 29985792;   // 25,600,000 -> end 55,585,792

// params block element offsets (w1/w2 stored PRE-SWIZZLED in B-fragment order)
#define PW1  0
#define PB1  16384
#define PG1  16640
#define PBB1 16896
#define PW2  17152
#define PB2  33536
#define PG2  33792
#define PBB2 34048
#define PFW  34304
#define PFB  37504
#define PTOT 37554
#define CVT_TOT (1280000 + PTOT)

// ---------------- runtime dtype detection (validated R4-R15) ----------------
__global__ void detect_kernel(const unsigned short* __restrict__ xu,
                              const unsigned int* __restrict__ mw,
                              int* __restrict__ cnts) {
    int tid = blockIdx.x * 256 + threadIdx.x;   // 16384 threads
    int insane = 0, lowp = 0, f32w = 0, gt1 = 0;
    for (int i = tid; i < 4096; i += 16384) {
        unsigned int u = xu[2 * i];
        if (((u >> 7) & 0xFFu) >= 0x90u) insane++;
    }
    for (int i = tid; i < 50000; i += 16384) {
        unsigned int w = mw[i];
        if ((w & 0xFFFFu) == 0x3F80u) lowp = 1;
        else if (w == 0x3F800000u) f32w = 1;
        else if (w > 1u) gt1 = 1;
    }
    if (insane) atomicAdd(&cnts[0], insane);
    if (lowp)   atomicOr(&cnts[1], 1);
    if (f32w)   atomicOr(&cnts[2], 1);
    if (gt1)    atomicOr(&cnts[3], 1);
}

__device__ inline bf16 ld_any(const void* p, int i, int f32mode) {
    if (f32mode) return (bf16)((const float*)p)[i];
    return ((const bf16*)p)[i];
}

__device__ inline int mask_dropped(const void* maskp, const int* cnts, size_t idx) {
    int w = cnts[1] ? 2 : (cnts[2] ? 4 : (cnts[3] ? 1 : 4));
    if (w == 1) return ((const unsigned char*)maskp)[idx] != 0;
    if (w == 2) return ((const unsigned short*)maskp)[idx] != 0;
    return ((const unsigned int*)maskp)[idx] != 0;
}

// convert all float inputs to canonical bf16; w1/w2 written in per-lane
// B-fragment order:
//   Wf[((nt*2+c)*64 + lane)*8 + j] = W[(c*32+(lane>>4)*8+j)*64 + nt*16+(lane&15)]
__global__ void convert_kernel(const int* __restrict__ cnts,
                               const void* x, const void* w1, const void* b1,
                               const void* g1, const void* bb1, const void* w2,
                               const void* b2, const void* g2, const void* bb2,
                               const void* fw, const void* fb,
                               bf16* __restrict__ xb, bf16* __restrict__ params) {
    int t = blockIdx.x * 256 + threadIdx.x;
    if (t >= CVT_TOT) return;
    int f = cnts[0] > 64;
    if (t < 1280000) { xb[t] = ld_any(x, t, f); return; }
    int u = t - 1280000;
    if (u < PB1 || (u >= PW2 && u < PB2)) {       // swizzled weight regions
        const void* src = (u < PB1) ? w1 : w2;
        int v = (u < PB1) ? u : u - PW2;
        int layer = v >> 12, rem = v & 4095;
        int j = rem & 7, lane = (rem >> 3) & 63, ntc = rem >> 9;
        int nt = ntc >> 1, c = ntc & 1;
        int k = c * 32 + (lane >> 4) * 8 + j;
        int n = nt * 16 + (lane & 15);
        params[u] = ld_any(src, layer * 4096 + k * 64 + n, f);
        return;
    }
    const void* src; int base;
    if      (u < PG1)  { src = b1;  base = PB1; }
    else if (u < PBB1) { src = g1;  base = PG1; }
    else if (u < PW2)  { src = bb1; base = PBB1; }
    else if (u < PG2)  { src = b2;  base = PB2; }
    else if (u < PBB2) { src = g2;  base = PG2; }
    else if (u < PFW)  { src = bb2; base = PBB2; }
    else if (u < PFB)  { src = fw;  base = PFW; }
    else               { src = fb;  base = PFB; }
    params[u] = ld_any(src, u - base, f);
}

// level-0 pool (algebraic, LDS graph slots) + pack 10-bit drop masks kb[n].
__global__ __launch_bounds__(256) void pool0_kernel(const bf16* __restrict__ xb,
                                                    const void* __restrict__ maskp,
                                                    const int* __restrict__ cnts,
                                                    const int* __restrict__ batch,
                                                    float* __restrict__ pooled,
                                                    int* __restrict__ kb) {
    __shared__ float lp[P0_SLOTS][64];
    __shared__ float lcnt[P0_NPB];
    __shared__ int gfirst;
    int tid = threadIdx.x;
    for (int i = tid; i < P0_SLOTS * 64; i += 256) ((float*)lp)[i] = 0.f;
    if (tid == 0) gfirst = batch[blockIdx.x * P0_NPB];
    if (tid < P0_NPB) {
        int n = blockIdx.x * P0_NPB + tid;
        int cnt = 0, kbv = 0;
        #pragma unroll
        for (int r = 0; r < R_RUNS; ++r) {
            int d = mask_dropped(maskp, cnts, (size_t)r * N_NODES + n);
            kbv |= d << r;
            cnt += !d;
        }
        lcnt[tid] = (float)cnt * (1.0f / R_RUNS);
        kb[n] = kbv;
    }
    __syncthreads();
    int c = tid & 7, ln = tid >> 3;
    int n = blockIdx.x * P0_NPB + ln;
    bf16x8 xv = *(const bf16x8*)(xb + (size_t)n * HID + c * 8);
    float sc = lcnt[ln];
    int g = batch[n];
    int slot = g - gfirst;
    if (slot < P0_SLOTS) {
        #pragma unroll
        for (int j = 0; j < 8; ++j)
            atomicAdd(&lp[slot][c * 8 + j], (float)xv[j] * sc);
    } else {
        #pragma unroll
        for (int j = 0; j < 8; ++j)
            atomicAdd(&pooled[g * HID + c * 8 + j], (float)xv[j] * sc);
    }
    __syncthreads();
    for (int s = tid >> 6; s < P0_SLOTS; s += 4) {
        int f = tid & 63;
        float v = lp[s][f];
        if (v != 0.f) atomicAdd(&pooled[(gfirst + s) * HID + f], v);
    }
}

// ---------------- CSR build (keyed by dst) ----------------
__global__ void csr_count_kernel(const int* __restrict__ ei, int* __restrict__ deg) {
    int e = blockIdx.x * 256 + threadIdx.x;
    if (e < N_EDGES) atomicAdd(&deg[ei[N_EDGES + e]], 1);
}

__global__ void csr_scan_kernel(int* __restrict__ deg, int* __restrict__ row_start) {
    __shared__ int lds[1024];
    int tid = threadIdx.x;
    const int CH = 20;
    int base = tid * CH;
    int local[CH];
    int s = 0;
    #pragma unroll
    for (int j = 0; j < CH; ++j) {
        int n = base + j;
        int d = (n < N_NODES) ? deg[n] : 0;
        local[j] = d; s += d;
    }
    lds[tid] = s; __syncthreads();
    for (int off = 1; off < 1024; off <<= 1) {
        int add = (tid >= off) ? lds[tid - off] : 0;
        __syncthreads();
        lds[tid] += add;
        __syncthreads();
    }
    int excl = lds[tid] - s;
    #pragma unroll
    for (int j = 0; j < CH; ++j) {
        int n = base + j;
        if (n < N_NODES) { row_start[n] = excl; deg[n] = excl; excl += local[j]; }
    }
    if (tid == 1023) row_start[N_NODES] = lds[1023];
}

__global__ void csr_fill_kernel(const int* __restrict__ ei, int* __restrict__ cursor,
                                int* __restrict__ col) {
    int e = blockIdx.x * 256 + threadIdx.x;
    if (e < N_EDGES) {
        int src = ei[e];
        int dst = ei[N_EDGES + e];
        int pos = atomicAdd(&cursor[dst], 1);
        col[pos] = src;
    }
}

// ---------------- LAYER-1 fused agg+gemm1 (R15-proven): h0 never materialized.
__global__ __launch_bounds__(256) void ag1_l1_kernel(const uint32* __restrict__ xbD,
                                                     const int* __restrict__ kb,
                                                     const int* __restrict__ row_start,
                                                     const int* __restrict__ col,
                                                     const bf16* __restrict__ Wf,
                                                     const bf16* __restrict__ bias,
                                                     bf16* __restrict__ out,
                                                     float* __restrict__ statsOut) {
    __shared__ __align__(16) bf16 zT[AG_NPB * R_RUNS * TS];
    __shared__ float lsum[64], lsq[64];
    uint32* zTu = (uint32*)zT;
    int tid = threadIdx.x;
    int wave = tid >> 6, lane = tid & 63, l16 = lane & 15, quad = lane >> 4;
    int p = lane & 31, hf = lane >> 5;
    int b = blockIdx.x;

    if (tid < 64) { lsum[tid] = 0.f; lsq[tid] = 0.f; }

    for (int i = 0; i < AG_NPB / 4; ++i) {
        int nl = wave + 4 * i;
        int n = b * AG_NPB + nl;
        float ax[R_RUNS], ay[R_RUNS];
        {
            uint32 xs = xbD[(size_t)n * 32 + p];
            int ms = kb[n];
            float fx = blo(xs), fy = bhi(xs);
            #pragma unroll
            for (int r = 0; r < R_RUNS; ++r) {
                int keep = (hf == 0) && !((ms >> r) & 1);
                ax[r] = keep ? fx : 0.f;
                ay[r] = keep ? fy : 0.f;
            }
        }
        int beg = row_start[n], end = row_start[n + 1];
        int iters = (end - beg + 1) >> 1;
        int k = 0;
        for (; k + 4 <= iters; k += 4) {
            uint32 xv[4]; int mv[4];
            #pragma unroll
            for (int u = 0; u < 4; ++u) {
                int idx = beg + 2 * (k + u) + hf;
                int valid = idx < end;
                int j = valid ? col[idx] : n;
                xv[u] = xbD[(size_t)j * 32 + p];
                mv[u] = valid ? kb[j] : 0x3FF;
            }
            #pragma unroll
            for (int u = 0; u < 4; ++u) {
                float fx = blo(xv[u]), fy = bhi(xv[u]);
                #pragma unroll
                for (int r = 0; r < R_RUNS; ++r)
                    if (!((mv[u] >> r) & 1)) { ax[r] += fx; ay[r] += fy; }
            }
        }
        for (; k < iters; ++k) {
            int idx = beg + 2 * k + hf;
            int valid = idx < end;
            int j = valid ? col[idx] : n;
            uint32 xv = xbD[(size_t)j * 32 + p];
            int mv = valid ? kb[j] : 0x3FF;
            float fx = blo(xv), fy = bhi(xv);
            #pragma unroll
            for (int r = 0; r < R_RUNS; ++r)
                if (!((mv >> r) & 1)) { ax[r] += fx; ay[r] += fy; }
        }
        #pragma unroll
        for (int r = 0; r < R_RUNS; ++r) {
            ax[r] += __shfl_xor(ax[r], 32);
            ay[r] += __shfl_xor(ay[r], 32);
        }
        #pragma unroll
        for (int q = 0; q < 5; ++q) {
            int r = hf * 5 + q;
            unsigned short lo = __builtin_bit_cast(unsigned short, (bf16)ax[r]);
            unsigned short hi = __builtin_bit_cast(unsigned short, (bf16)ay[r]);
            zTu[(nl * R_RUNS + r) * (TS / 2) + p] = (uint32)lo | ((uint32)hi << 16);
        }
    }
    __syncthreads();

    bf16x8 bfr[4][2];
    #pragma unroll
    for (int nt = 0; nt < 4; ++nt)
        #pragma unroll
        for (int c = 0; c < 2; ++c)
            bfr[nt][c] = *(const bf16x8*)(Wf + (size_t)((nt * 2 + c) * 64 + lane) * 8);
    float bvs[4];
    #pragma unroll
    for (int nt = 0; nt < 4; ++nt) bvs[nt] = (float)bias[nt * 16 + l16];

    for (int g = wave; g < 5; g += 4) {
        const bf16* tp = &zT[(g * 16 + l16) * TS];
        bf16x8 a0 = *(const bf16x8*)(tp + quad * 8);
        bf16x8 a1 = *(const bf16x8*)(tp + 32 + quad * 8);
        f32x4 acc[4];
        #pragma unroll
        for (int nt = 0; nt < 4; ++nt) acc[nt] = (f32x4){bvs[nt], bvs[nt], bvs[nt], bvs[nt]};
        #pragma unroll
        for (int nt = 0; nt < 4; ++nt) {
            acc[nt] = __builtin_amdgcn_mfma_f32_16x16x32_bf16(a0, bfr[nt][0], acc[nt], 0, 0, 0);
            acc[nt] = __builtin_amdgcn_mfma_f32_16x16x32_bf16(a1, bfr[nt][1], acc[nt], 0, 0, 0);
        }
        size_t rowBase = (size_t)b * (AG_NPB * R_RUNS) + g * 16;
        #pragma unroll
        for (int nt = 0; nt < 4; ++nt) {
            float ss = 0.f, qq = 0.f;
            #pragma unroll
            for (int reg = 0; reg < 4; ++reg) {
                float v = acc[nt][reg];
                ss += v; qq += v * v;
                out[(rowBase + quad * 4 + reg) * HID + nt * 16 + l16] = (bf16)v;
            }
            atomicAdd(&lsum[nt * 16 + l16], ss);
            atomicAdd(&lsq[nt * 16 + l16], qq);
        }
    }
    __syncthreads();
    if (tid < 64) {
        int copy = b & (NCOPY - 1);
        atomicAdd(&statsOut[copy * 128 + tid], lsum[tid]);
        atomicAdd(&statsOut[copy * 128 + 64 + tid], lsq[tid]);
    }
}

// ---------------- layers 2-4 fused agg + gemm1: R16 = 512 threads (8 waves),
// one node per wave in phase 1 (split-agg's 62%-occupancy shape) — tests the
// blocks/CU residency hypothesis (R15: 4-wave blocks stuck at 34% occ).
__global__ __launch_bounds__(512) void ag1_kernel(const uint32* __restrict__ hD,
                                                  const int* __restrict__ row_start,
                                                  const int* __restrict__ col,
                                                  const bf16* __restrict__ Wf,
                                                  const bf16* __restrict__ bias,
                                                  bf16* __restrict__ out,
                                                  float* __restrict__ statsOut) {
    __shared__ __align__(16) bf16 zT[AG_NPB * R_RUNS * TS];   // 80 x 72 = 11520 B
    __shared__ float lsum[64], lsq[64];
    uint32* zTu = (uint32*)zT;                                // row stride 36 dwords
    int tid = threadIdx.x;
    int wave = tid >> 6, lane = tid & 63, l16 = lane & 15, quad = lane >> 4;
    int b = blockIdx.x;
    const int NODE_DW = R_RUNS * HID / 2;   // 320

    if (tid < 64) { lsum[tid] = 0.f; lsq[tid] = 0.f; }

    {   // ---- phase 1: one node per wave
        int nl = wave;                      // 0..7
        int n = b * AG_NPB + nl;
        size_t base4 = (size_t)n * NODE_DW + lane * 4;
        size_t baset = (size_t)n * NODE_DW + 256 + lane;
        float acc[10];
        {
            uint4 u = *(const uint4*)(hD + base4);
            uint32 tw = hD[baset];
            acc[0] = blo(u.x); acc[1] = bhi(u.x);
            acc[2] = blo(u.y); acc[3] = bhi(u.y);
            acc[4] = blo(u.z); acc[5] = bhi(u.z);
            acc[6] = blo(u.w); acc[7] = bhi(u.w);
            acc[8] = blo(tw);  acc[9] = bhi(tw);
        }
        int beg = row_start[n], end = row_start[n + 1];
        int idx = beg;
        for (; idx + 4 <= end; idx += 4) {
            uint4 a[4]; uint32 tw[4];
            #pragma unroll
            for (int u = 0; u < 4; ++u) {
                size_t o = (size_t)col[idx + u] * NODE_DW;
                a[u] = *(const uint4*)(hD + o + lane * 4);
                tw[u] = hD[o + 256 + lane];
            }
            #pragma unroll
            for (int u = 0; u < 4; ++u) {
                uint32 wd[4] = {a[u].x, a[u].y, a[u].z, a[u].w};
                #pragma unroll
                for (int c = 0; c < 4; ++c) {
                    acc[2 * c]     += blo(wd[c]);
                    acc[2 * c + 1] += bhi(wd[c]);
                }
                acc[8] += blo(tw[u]);
                acc[9] += bhi(tw[u]);
            }
        }
        for (; idx < end; ++idx) {
            size_t o = (size_t)col[idx] * NODE_DW;
            uint4 a0 = *(const uint4*)(hD + o + lane * 4);
            uint32 t0 = hD[o + 256 + lane];
            uint32 wd[4] = {a0.x, a0.y, a0.z, a0.w};
            #pragma unroll
            for (int c = 0; c < 4; ++c) {
                acc[2 * c]     += blo(wd[c]);
                acc[2 * c + 1] += bhi(wd[c]);
            }
            acc[8] += blo(t0);
            acc[9] += bhi(t0);
        }
        #pragma unroll
        for (int c = 0; c < 5; ++c) {
            int d = (c < 4) ? (lane * 4 + c) : (256 + lane);
            int rL = nl * R_RUNS + (d >> 5);
            int fp = d & 31;
            unsigned short lo = __builtin_bit_cast(unsigned short, (bf16)acc[2 * c]);
            unsigned short hi = __builtin_bit_cast(unsigned short, (bf16)acc[2 * c + 1]);
            zTu[rL * (TS / 2) + fp] = (uint32)lo | ((uint32)hi << 16);
        }
    }
    __syncthreads();

    // ---- phase 2: 5 row-groups of 16 over waves 0-4
    if (wave < 5) {
        bf16x8 bfr[4][2];
        #pragma unroll
        for (int nt = 0; nt < 4; ++nt)
            #pragma unroll
            for (int c = 0; c < 2; ++c)
                bfr[nt][c] = *(const bf16x8*)(Wf + (size_t)((nt * 2 + c) * 64 + lane) * 8);
        int g = wave;
        const bf16* tp = &zT[(g * 16 + l16) * TS];
        bf16x8 a0 = *(const bf16x8*)(tp + quad * 8);
        bf16x8 a1 = *(const bf16x8*)(tp + 32 + quad * 8);
        f32x4 acc[4];
        #pragma unroll
        for (int nt = 0; nt < 4; ++nt) {
            float bv = (float)bias[nt * 16 + l16];
            acc[nt] = (f32x4){bv, bv, bv, bv};
        }
        #pragma unroll
        for (int nt = 0; nt < 4; ++nt) {
            acc[nt] = __builtin_amdgcn_mfma_f32_16x16x32_bf16(a0, bfr[nt][0], acc[nt], 0, 0, 0);
            acc[nt] = __builtin_amdgcn_mfma_f32_16x16x32_bf16(a1, bfr[nt][1], acc[nt], 0, 0, 0);
        }
        size_t rowBase = (size_t)b * (AG_NPB * R_RUNS) + g * 16;
        #pragma unroll
        for (int nt = 0; nt < 4; ++nt) {
            float ss = 0.f, qq = 0.f;
            #pragma unroll
            for (int reg = 0; reg < 4; ++reg) {
                float v = acc[nt][reg];
                ss += v; qq += v * v;
                out[(rowBase + quad * 4 + reg) * HID + nt * 16 + l16] = (bf16)v;
            }
            atomicAdd(&lsum[nt * 16 + l16], ss);
            atomicAdd(&lsq[nt * 16 + l16], qq);
        }
    }
    __syncthreads();
    if (tid < 64) {
        int copy = b & (NCOPY - 1);
        atomicAdd(&statsOut[copy * 128 + tid], lsum[tid]);
        atomicAdd(&statsOut[copy * 128 + 64 + tid], lsq[tid]);
    }
}

// ---------------- gemm2: 320 rows/block (5 tiles of 64), grid 625 (R12-proven).
__global__ __launch_bounds__(256) void gemm64_kernel(const bf16* in,
                                                     const bf16* __restrict__ Wf,
                                                     const bf16* __restrict__ bias,
                                                     bf16* out,
                                                     const float* __restrict__ statsIn,
                                                     const bf16* __restrict__ gammaIn,
                                                     const bf16* __restrict__ betaIn,
                                                     float* __restrict__ statsOut) {
    __shared__ float lstat[128];
    __shared__ float lscale[64], lshift[64];
    __shared__ float lsum[64], lsq[64];
    int tid = threadIdx.x;
    int wave = tid >> 6, lane = tid & 63, l16 = lane & 15, quad = lane >> 4;

    if (tid < 128) {
        float s = 0.f;
        #pragma unroll
        for (int k = 0; k < NCOPY; ++k) s += statsIn[k * 128 + tid];
        lstat[tid] = s;
    }
    if (tid < 64) { lsum[tid] = 0.f; lsq[tid] = 0.f; }
    __syncthreads();
    if (tid < 64) {
        float mu = lstat[tid] * (1.0f / MROWS);
        float var = lstat[tid + 64] * (1.0f / MROWS) - mu * mu;
        float rs = rsqrtf(var + BN_EPS);
        float a = (float)gammaIn[tid] * rs;
        lscale[tid] = a;
        lshift[tid] = (float)betaIn[tid] - mu * a;
    }
    __syncthreads();

    bf16x8 bfrag[4][2];
    #pragma unroll
    for (int nt = 0; nt < 4; ++nt)
        #pragma unroll
        for (int c = 0; c < 2; ++c)
            bfrag[nt][c] = *(const bf16x8*)(Wf + (size_t)((nt * 2 + c) * 64 + lane) * 8);
    float bvs[4];
    #pragma unroll
    for (int nt = 0; nt < 4; ++nt) bvs[nt] = (float)bias[nt * 16 + l16];

    for (int t5 = 0; t5 < G2_TILES; ++t5) {
        size_t rowBase = (size_t)blockIdx.x * (G2_TILES * 64) + t5 * 64 + wave * 16;
        f32x4 acc[4];
        #pragma unroll
        for (int nt = 0; nt < 4; ++nt) acc[nt] = (f32x4){bvs[nt], bvs[nt], bvs[nt], bvs[nt]};

        size_t row = rowBase + l16;
        bf16x8 afrag[2];
        #pragma unroll
        for (int c = 0; c < 2; ++c) {
            int k0 = c * 32 + quad * 8;
            bf16x8 v = *(const bf16x8*)(in + row * HID + k0);
            #pragma unroll
            for (int j = 0; j < 8; ++j) {
                float f = (float)v[j] * lscale[k0 + j] + lshift[k0 + j];
                v[j] = (bf16)fmaxf(f, 0.f);
            }
            afrag[c] = v;
        }

        #pragma unroll
        for (int nt = 0; nt < 4; ++nt) {
            acc[nt] = __builtin_amdgcn_mfma_f32_16x16x32_bf16(afrag[0], bfrag[nt][0], acc[nt], 0, 0, 0);
            acc[nt] = __builtin_amdgcn_mfma_f32_16x16x32_bf16(afrag[1], bfrag[nt][1], acc[nt], 0, 0, 0);
        }

        #pragma unroll
        for (int nt = 0; nt < 4; ++nt) {
            float s = 0.f, q = 0.f;
            #pragma unroll
            for (int reg = 0; reg < 4; ++reg) {
                float v = acc[nt][reg];
                s += v; q += v * v;
                out[(rowBase + quad * 4 + reg) * HID + nt * 16 + l16] = (bf16)v;
            }
            atomicAdd(&lsum[nt * 16 + l16], s);
            atomicAdd(&lsq[nt * 16 + l16], q);
        }
    }
    __syncthreads();
    if (tid < 64) {
        int copy = blockIdx.x & (NCOPY - 1);
        atomicAdd(&statsOut[copy * 128 + tid], lsum[tid]);
        atomicAdd(&statsOut[copy * 128 + 64 + tid], lsq[tid]);
    }
}

// fused stats reduce + BN+ReLU + h-materialize + pool (R14-proven form).
__global__ __launch_bounds__(256) void pool_bn_kernel(const bf16* __restrict__ t,
                                                      const float* __restrict__ statsIn,
                                                      const bf16* __restrict__ gammaIn,
                                                      const bf16* __restrict__ betaIn,
                                                      bf16* __restrict__ hOut,
                                                      const int* __restrict__ batch,
                                                      float* __restrict__ pooled) {
    __shared__ float lstat[128], lscale[64], lshift[64];
    __shared__ float lp[PB_SLOTS][64];
    __shared__ int gfirst;
    int tid = threadIdx.x;
    if (tid < 128) {
        float s = 0.f;
        #pragma unroll
        for (int k = 0; k < NCOPY; ++k) s += statsIn[k * 128 + tid];
        lstat[tid] = s;
    }
    for (int i = tid; i < PB_SLOTS * 64; i += 256) ((float*)lp)[i] = 0.f;
    if (tid == 0) gfirst = batch[blockIdx.x * PB_NPB];
    __syncthreads();
    if (tid < 64) {
        float mu = lstat[tid] * (1.0f / MROWS);
        float var = lstat[tid + 64] * (1.0f / MROWS) - mu * mu;
        float rs = rsqrtf(var + BN_EPS);
        float a = (float)gammaIn[tid] * rs;
        lscale[tid] = a;
        lshift[tid] = (float)betaIn[tid] - mu * a;
    }
    __syncthreads();
    int f = tid & 63, nsub = tid >> 6;
    float sc = lscale[f], sh = lshift[f];
    #pragma unroll
    for (int j = 0; j < PB_NPB / 4; ++j) {
        int n = blockIdx.x * PB_NPB + j * 4 + nsub;
        size_t base = (size_t)n * (R_RUNS * HID) + f;
        float s = 0.f;
        #pragma unroll
        for (int r = 0; r < R_RUNS; ++r) {
            float v = (float)t[base + r * HID];
            v = fmaxf(v * sc + sh, 0.f);
            hOut[base + r * HID] = (bf16)v;
            s += v;
        }
        int g = batch[n];
        int slot = g - gfirst;
        if (slot < PB_SLOTS) atomicAdd(&lp[slot][f], s * (1.0f / R_RUNS));
        else                 atomicAdd(&pooled[g * HID + f], s * (1.0f / R_RUNS));
    }
    __syncthreads();
    for (int s = tid >> 6; s < PB_SLOTS; s += 4) {
        float v = lp[s][tid & 63];
        if (v != 0.f) atomicAdd(&pooled[(gfirst + s) * HID + (tid & 63)], v);
    }
}

// final: out[g,:] = log_softmax( sum_l pooled5[l][g] @ fcw_l + fcb_l )
__global__ void fc_softmax_kernel(const float* __restrict__ pooled5,
                                  const bf16* __restrict__ params,
                                  const int* __restrict__ cnts, void* __restrict__ out) {
    int g = threadIdx.x;   // 128 threads
    if (g >= NG) return;
    float o[NC];
    #pragma unroll
    for (int c = 0; c < NC; ++c) o[c] = 0.f;
    for (int l = 0; l < NL + 1; ++l) {
        const float* pg = pooled5 + ((size_t)l * NG + g) * HID;
        const bf16* fw = params + PFW + l * (HID * NC);
        for (int k = 0; k < HID; ++k) {
            float p = pg[k];
            #pragma unroll
            for (int c = 0; c < NC; ++c) o[c] += p * (float)fw[k * NC + c];
        }
        #pragma unroll
        for (int c = 0; c < NC; ++c) o[c] += (float)params[PFB + l * NC + c];
    }
    float m = -1e30f;
    #pragma unroll
    for (int c = 0; c < NC; ++c) m = fmaxf(m, o[c]);
    float s = 0.f;
    #pragma unroll
    for (int c = 0; c < NC; ++c) s += expf(o[c] - m);
    float lg = logf(s);
    int f = cnts[0] > 64;
    #pragma unroll
    for (int c = 0; c < NC; ++c) {
        float val = o[c] - m - lg;
        if (f) ((float*)out)[g * NC + c] = val;
        else   ((bf16*)out)[g * NC + c] = (bf16)val;
    }
}

extern "C" void kernel_launch(void* const* d_in, const int* in_sizes, int n_in,
                              void* d_out, int out_size, void* d_ws, size_t ws_size,
                              hipStream_t stream) {
    const void* x     = d_in[0];
    const int*  ei    = (const int*)d_in[1];
    const int*  batch = (const int*)d_in[2];
    const void* maskp = d_in[3];

    char* ws = (char*)d_ws;
    int*   cnts    = (int*)(ws + OFF_FLAGS);
    int*   cursor  = (int*)(ws + OFF_CURSOR);
    float* statsb  = (float*)(ws + OFF_STATS);
    float* pooled5 = (float*)(ws + OFF_POOLED5);
    int*   rowst   = (int*)(ws + OFF_ROWST);
    int*   colbuf  = (int*)(ws + OFF_COL);
    int*   kbuf    = (int*)(ws + OFF_KB);
    bf16*  params  = (bf16*)(ws + OFF_PARAMS);
    bf16*  xb      = (bf16*)(ws + OFF_XB);
    bf16*  h       = (bf16*)(ws + OFF_H);
    bf16*  z       = (bf16*)(ws + OFF_Z);

    hipMemsetAsync(ws, 0, ZERO_BYTES, stream);   // flags+cursor+stats+pooled5

    detect_kernel<<<64, 256, 0, stream>>>((const unsigned short*)x,
                                          (const unsigned int*)maskp, cnts);
    convert_kernel<<<(CVT_TOT + 255) / 256, 256, 0, stream>>>(
        cnts, x, d_in[4], d_in[5], d_in[6], d_in[7], d_in[8], d_in[9], d_in[10],
        d_in[11], d_in[12], d_in[13], xb, params);

    csr_count_kernel<<<(N_EDGES + 255) / 256, 256, 0, stream>>>(ei, cursor);
    csr_scan_kernel<<<1, 1024, 0, stream>>>(cursor, rowst);
    csr_fill_kernel<<<(N_EDGES + 255) / 256, 256, 0, stream>>>(ei, cursor, colbuf);

    pool0_kernel<<<N_NODES / P0_NPB, 256, 0, stream>>>(xb, maskp, cnts, batch,
                                                       pooled5, kbuf);

    for (int i = 0; i < NL; ++i) {
        float* st1 = statsb + (size_t)(2 * i) * (NCOPY * 128);
        float* st2 = statsb + (size_t)(2 * i + 1) * (NCOPY * 128);

        if (i == 0) {
            ag1_l1_kernel<<<N_NODES / AG_NPB, 256, 0, stream>>>(
                (const uint32*)xb, kbuf, rowst, colbuf,
                params + PW1, params + PB1, z, st1);
        } else {
            ag1_kernel<<<N_NODES / AG_NPB, 512, 0, stream>>>(
                (const uint32*)h, rowst, colbuf,
                params + PW1 + i * 4096, params + PB1 + i * 64, z, st1);
        }

        gemm64_kernel<<<MROWS / (G2_TILES * 64), 256, 0, stream>>>(
            z, params + PW2 + i * 4096, params + PB2 + i * 64, z,
            st1, params + PG1 + i * 64, params + PBB1 + i * 64, st2);

        pool_bn_kernel<<<N_NODES / PB_NPB, 256, 0, stream>>>(
            z, st2, params + PG2 + i * 64, params + PBB2 + i * 64, h, batch,
            pooled5 + (size_t)(i + 1) * NG * HID);
    }

    fc_softmax_kernel<<<1, 128, 0, stream>>>(pooled5, params, cnts, d_out);
}